// Round 15
// baseline (7867.741 us; speedup 1.0000x reference)
//
#include <hip/hip_runtime.h>

#define B_ 64
#define S_ 1024
#define H_ 768
#define GB 8    // batch groups (8 rows each)
#define CB 6    // col-blocks per group (128 cols each)

typedef short s16x8 __attribute__((ext_vector_type(8)));
typedef float f32x4 __attribute__((ext_vector_type(4)));
typedef unsigned u32x4 __attribute__((ext_vector_type(4)));

__device__ __forceinline__ unsigned short f2b(float f) {
  unsigned u = __builtin_bit_cast(unsigned, f);
  u += 0x7FFFu + ((u >> 16) & 1u);
  return (unsigned short)(u >> 16);
}
__device__ __forceinline__ float b2f(unsigned short h) {
  unsigned u = ((unsigned)h) << 16;
  return __builtin_bit_cast(float, u);
}

// tanh(x) = 1 - 2/(1+e^{2x}); exact at +-inf, ~1e-7 rel err, no branches.
__device__ __forceinline__ float fast_tanh(float x) {
  float e = __builtin_amdgcn_exp2f(x * 2.8853900817779268f);  // e^{2x}
  return 1.0f - 2.0f * __builtin_amdgcn_rcpf(1.0f + e);
}

__global__ void conv_f2b_kernel(const float* __restrict__ src,
                                unsigned short* __restrict__ dst, int n) {
  int i = (blockIdx.x * blockDim.x + threadIdx.x) * 4;
  if (i >= n) return;
  float4 v = *(const float4*)(src + i);
  unsigned long long p = (unsigned long long)f2b(v.x)
      | ((unsigned long long)f2b(v.y) << 16)
      | ((unsigned long long)f2b(v.z) << 32)
      | ((unsigned long long)f2b(v.w) << 48);
  *(unsigned long long*)(dst + i) = p;
}

__global__ void tail_kernel(const unsigned short* __restrict__ src,
                            float* __restrict__ dst, int n) {
  int i = blockIdx.x * blockDim.x + threadIdx.x;
  if (i < n) dst[i] = b2f(src[i]);
}

// C[r][n] = sum_k A[r][k] * W[n][k] + bias (MODE0: A fp32 x, bias1+bias2).
template <int MODE>
__global__ __launch_bounds__(256) void gemm_kernel(
    const void* __restrict__ Aptr, const unsigned short* __restrict__ Bw,
    float* __restrict__ C, const float* __restrict__ bias1,
    const float* __restrict__ bias2) {
  __shared__ unsigned short As[128 * 64];
  __shared__ unsigned short Bs[128 * 64];
  const int tid = threadIdx.x;
  const int l = tid & 63;
  const int w = tid >> 6;
  const int wm = w >> 1, wn = w & 1;
  const int r0 = blockIdx.x * 128;
  const int n0 = blockIdx.y * 128;
  const int row16 = l & 15;
  const int g4 = l >> 4;
  const int swz = (l & 7) << 3;

  const int srow = tid >> 1;
  const int shalf = (tid & 1) * 32;
  size_t a_off = (size_t)(r0 + srow) * 768;
  const size_t b_off = (size_t)(n0 + srow) * 768;
  const int swrow = (srow & 7) << 3;

  f32x4 acc[4][4] = {};

  for (int k0 = 0; k0 < 768; k0 += 64) {
    {
      const float* Af = (const float*)Aptr + a_off + k0 + shalf;
#pragma unroll
      for (int jj = 0; jj < 4; ++jj) {
        float4 v0 = *(const float4*)(Af + jj * 8);
        float4 v1 = *(const float4*)(Af + jj * 8 + 4);
        uint4 p;
        p.x = f2b(v0.x) | ((unsigned)f2b(v0.y) << 16);
        p.y = f2b(v0.z) | ((unsigned)f2b(v0.w) << 16);
        p.z = f2b(v1.x) | ((unsigned)f2b(v1.y) << 16);
        p.w = f2b(v1.z) | ((unsigned)f2b(v1.w) << 16);
        int c = (shalf + jj * 8) ^ swrow;
        *(uint4*)(As + srow * 64 + c) = p;
      }
    }
    {
      const unsigned short* Bb = Bw + b_off + k0 + shalf;
#pragma unroll
      for (int jj = 0; jj < 4; ++jj) {
        uint4 p = *(const uint4*)(Bb + jj * 8);
        int c = (shalf + jj * 8) ^ swrow;
        *(uint4*)(Bs + srow * 64 + c) = p;
      }
    }
    __syncthreads();
#pragma unroll
    for (int kb = 0; kb < 2; ++kb) {
      int ccol = (kb * 32 + g4 * 8) ^ swz;
      s16x8 af[4], bfr[4];
#pragma unroll
      for (int mi = 0; mi < 4; ++mi)
        af[mi] = __builtin_bit_cast(
            s16x8, *(const uint4*)(As + (wm * 64 + mi * 16 + row16) * 64 + ccol));
#pragma unroll
      for (int ni = 0; ni < 4; ++ni)
        bfr[ni] = __builtin_bit_cast(
            s16x8, *(const uint4*)(Bs + (wn * 64 + ni * 16 + row16) * 64 + ccol));
#pragma unroll
      for (int mi = 0; mi < 4; ++mi)
#pragma unroll
        for (int ni = 0; ni < 4; ++ni)
          acc[mi][ni] = __builtin_amdgcn_mfma_f32_16x16x32_bf16(
              af[mi], bfr[ni], acc[mi][ni], 0, 0, 0);
    }
    __syncthreads();
  }
#pragma unroll
  for (int ni = 0; ni < 4; ++ni) {
    int col = n0 + wn * 64 + ni * 16 + row16;
    float bv = bias1[col] + bias2[col];
#pragma unroll
    for (int mi = 0; mi < 4; ++mi) {
      int rbase = r0 + wm * 64 + mi * 16 + g4 * 4;
#pragma unroll
      for (int i = 0; i < 4; ++i)
        C[(size_t)(rbase + i) * 768 + col] = acc[mi][ni][i] + bv;
    }
  }
}

// Persistent recurrence + FUSED logits (R15): 48 blocks = 8 batch-groups
// (8 rows) x 6 col-blocks (128 cols), 512 threads.  Protocol = R14 proven
// (data-as-flag sc1/IF, zero-sentinel, memset-zeroed slab, self-staged own
// cols, paired 16B stores, 16-slot read swizzle with don't-care lanes).
// R15 delta: after the h-update store is issued, each wave computes the
// logits tile for s=t-1 (16 n-cols x its group's rows) using the COMPLETE
// h(t) row already in the LDS slab (B re-read from LDS so registers
// recycle) and W_fc fragments streamed from L2.  The extra 24 MFMAs + 24
// L2 loads hide in the ~4000-cycle poll-wait for step t+1.  Iteration
// t=S_ is a poll-only epilogue producing the last logits row.  The
// standalone GEMM2 dispatch (~150us) disappears.  d_out WAR is safe: xp
// row (b,s) is read at step s; logits row (b,s) written at step s+1.
__global__ __launch_bounds__(512) void scan_kernel(
    const float* __restrict__ W_hh, const float* __restrict__ xp,
    unsigned short* __restrict__ hseq, const unsigned short* __restrict__ wfc,
    const float* __restrict__ b_fc, float* __restrict__ out) {
  __shared__ unsigned short hs[2][8 * 768];  // 2 x 12KB
  const int tid = threadIdx.x;
  const int l = tid & 63;
  const int w = tid >> 6;
  const int bg = blockIdx.x / CB;  // 0..7
  const int cb = blockIdx.x % CB;  // 0..5
  const int b0 = bg * 8;
  const int c0 = cb * 128;
  const int row16 = l & 15;
  const int row8 = row16 & 7;
  const int g4 = l >> 4;

  // pack W_hh fragments: A[row=l&15 (out col)][k = kb*32 + (l>>4)*8 + j]
  uint4 wfrag[24];
  {
    const float* wr = W_hh + (size_t)(c0 + w * 16 + row16) * 768;
#pragma unroll
    for (int kb = 0; kb < 24; ++kb) {
      int k0 = kb * 32 + g4 * 8;
      float4 v0 = *(const float4*)(wr + k0);
      float4 v1 = *(const float4*)(wr + k0 + 4);
      uint4 p;
      p.x = f2b(v0.x) | ((unsigned)f2b(v0.y) << 16);
      p.y = f2b(v0.z) | ((unsigned)f2b(v0.w) << 16);
      p.z = f2b(v1.x) | ((unsigned)f2b(v1.y) << 16);
      p.w = f2b(v1.z) | ((unsigned)f2b(v1.w) << 16);
      wfrag[kb] = p;
    }
  }

  // foreign-chunk geometry (t>=1): 80 foreign 16B chunks/row x 8 rows = 640
  const int c08 = cb * 16;
  const int nch = (tid < 128) ? 2 : 1;
  size_t gF[2];
  int lF[2];
#pragma unroll
  for (int j = 0; j < 2; ++j) {
    int fi = (j == 0) ? tid : (512 + (tid & 127));
    int row = fi / 80;
    int f = fi - row * 80;
    int col8 = f + (f >= c08 ? 16 : 0);
    gF[j] = (size_t)(b0 + row) * 768 + col8 * 8;
    lF[j] = row * 1536 + ((col8 * 16) ^ ((row & 7) << 4));
  }

  const size_t hcol = c0 + w * 16 + g4 * 4;
  unsigned short* hout_base = hseq + (size_t)(b0 + row8) * 768 + hcol;
  const float* xp_base = xp + (size_t)(b0 + row8) * 1024 * 768 + hcol;
  const int soff = row8 * 1536 + (((int)hcol * 2) ^ (row8 << 4));
  const int rswz = row16 << 4;  // 16-slot key; row16>=8 reads don't-care data
  const bool owner = (row16 < 8);

  // logits constants: wave computes n-cols c0+w*16 .. +15 for its 8 rows
  const unsigned short* wfcp = wfc + (size_t)(c0 + w * 16 + row16) * 768;
  const float4 bfcv = *(const float4*)(b_fc + c0 + w * 16 + g4 * 4);
  float* lout_base = out + (size_t)(b0 + row16) * 1024 * 768 + hcol;

  for (int t = 0; t <= S_; ++t) {
    char* lb = (char*)hs[t & 1];
    float4 xpv;
    if (t < S_) xpv = *(const float4*)(xp_base + (size_t)t * 768);
    const unsigned short* hin = hseq + (size_t)t * (B_ * H_);
    if (t == 0) {
      // h0 (= zeros) pre-written by conv kernel; full slab = 768 chunks.
      uint4 cv0[2];
      int nj = (tid < 256) ? 2 : 1;
#pragma unroll
      for (int j = 0; j < 2; ++j) {
        if (j < nj) {
          int ch = (j == 0) ? tid : (512 + (tid & 255));
          int row = ch / 96;
          int col8 = ch - row * 96;
          asm volatile("global_load_dwordx4 %0, %1, off sc1"
                       : "=&v"(cv0[j])
                       : "v"(hin + (size_t)(b0 + row) * 768 + col8 * 8));
        }
      }
      asm volatile("s_waitcnt vmcnt(0)" ::: "memory");
      __builtin_amdgcn_sched_barrier(0);
#pragma unroll
      for (int j = 0; j < 2; ++j) {
        if (j < nj) {
          int ch = (j == 0) ? tid : (512 + (tid & 255));
          int row = ch / 96;
          int col8 = ch - row * 96;
          *(uint4*)(lb + row * 1536 + ((col8 * 16) ^ ((row & 7) << 4))) =
              cv0[j];
        }
      }
    } else {
      uint4 cv[2];
      unsigned done = 0;
      const unsigned full = (nch == 2) ? 3u : 1u;
      while (done != full) {
        if (!(done & 1))
          asm volatile("global_load_dwordx4 %0, %1, off sc1"
                       : "=&v"(cv[0]) : "v"(hin + gF[0]));
        if (nch == 2 && !(done & 2))
          asm volatile("global_load_dwordx4 %0, %1, off sc1"
                       : "=&v"(cv[1]) : "v"(hin + gF[1]));
        asm volatile("s_waitcnt vmcnt(0)" ::: "memory");
        __builtin_amdgcn_sched_barrier(0);  // keep checks after the waitcnt
        if (!(done & 1) && (cv[0].x | cv[0].y) != 0 && (cv[0].z | cv[0].w) != 0) {
          done |= 1;
          *(uint4*)(lb + lF[0]) = cv[0];
        }
        if (nch == 2 && !(done & 2) && (cv[1].x | cv[1].y) != 0 &&
            (cv[1].z | cv[1].w) != 0) {
          done |= 2;
          *(uint4*)(lb + lF[1]) = cv[1];
        }
      }
    }
    __syncthreads();

    const char* rb = lb + row8 * 1536;
    if (t < S_) {
      uint4 hb[24];
#pragma unroll
      for (int kb = 0; kb < 24; ++kb)
        hb[kb] = *(const uint4*)(rb + ((kb * 64 + g4 * 16) ^ rswz));

      f32x4 acc0 = {xpv.x, xpv.y, xpv.z, xpv.w};
      f32x4 acc1 = {0.f, 0.f, 0.f, 0.f};
      f32x4 acc2 = {0.f, 0.f, 0.f, 0.f};
      f32x4 acc3 = {0.f, 0.f, 0.f, 0.f};
#pragma unroll
      for (int kb = 0; kb < 24; kb += 4) {
        acc0 = __builtin_amdgcn_mfma_f32_16x16x32_bf16(
            __builtin_bit_cast(s16x8, wfrag[kb]),
            __builtin_bit_cast(s16x8, hb[kb]), acc0, 0, 0, 0);
        acc1 = __builtin_amdgcn_mfma_f32_16x16x32_bf16(
            __builtin_bit_cast(s16x8, wfrag[kb + 1]),
            __builtin_bit_cast(s16x8, hb[kb + 1]), acc1, 0, 0, 0);
        acc2 = __builtin_amdgcn_mfma_f32_16x16x32_bf16(
            __builtin_bit_cast(s16x8, wfrag[kb + 2]),
            __builtin_bit_cast(s16x8, hb[kb + 2]), acc2, 0, 0, 0);
        acc3 = __builtin_amdgcn_mfma_f32_16x16x32_bf16(
            __builtin_bit_cast(s16x8, wfrag[kb + 3]),
            __builtin_bit_cast(s16x8, hb[kb + 3]), acc3, 0, 0, 0);
      }
      f32x4 g = (acc0 + acc1) + (acc2 + acc3);
      float t0 = fast_tanh(g[0]), t1 = fast_tanh(g[1]);
      float t2 = fast_tanh(g[2]), t3 = fast_tanh(g[3]);
      unsigned long long pk = (unsigned long long)f2b(t0)
          | ((unsigned long long)f2b(t1) << 16)
          | ((unsigned long long)f2b(t2) << 32)
          | ((unsigned long long)f2b(t3) << 48);
      if (pk == 0) pk = 1;  // readiness sentinel

      // self-stage own cols for step t+1 (single writer; rows 0..7 only)
      if (owner) *(unsigned long long*)((char*)hs[(t + 1) & 1] + soff) = pk;

      // paired 16B global store (lanes l, l^16; even-g4 owner lane stores)
      unsigned long long po = __shfl(pk, l ^ 16);
      if (owner && (g4 & 1) == 0) {
        u32x4 st;
        st[0] = (unsigned)pk;
        st[1] = (unsigned)(pk >> 32);
        st[2] = (unsigned)po;
        st[3] = (unsigned)(po >> 32);
        asm volatile("global_store_dwordx4 %0, %1, off sc1" ::"v"(
                         hout_base + (size_t)(t + 1) * (B_ * H_)),
                     "v"(st)
                     : "memory");
      }
    }

    // fused logits for s = t-1 (hides in the poll-wait for step t+1):
    // D[n=(g4*4+j)][b=row16] = sum_k W_fc[n][k] * h_t[b][k]
    if (t >= 1) {
      f32x4 lacc0 = {0.f, 0.f, 0.f, 0.f};
      f32x4 lacc1 = {0.f, 0.f, 0.f, 0.f};
#pragma unroll
      for (int kb = 0; kb < 24; kb += 2) {
        uint4 hbl0 = *(const uint4*)(rb + ((kb * 64 + g4 * 16) ^ rswz));
        uint4 hbl1 = *(const uint4*)(rb + (((kb + 1) * 64 + g4 * 16) ^ rswz));
        uint4 a0 = *(const uint4*)(wfcp + kb * 32 + g4 * 8);
        uint4 a1 = *(const uint4*)(wfcp + (kb + 1) * 32 + g4 * 8);
        lacc0 = __builtin_amdgcn_mfma_f32_16x16x32_bf16(
            __builtin_bit_cast(s16x8, a0), __builtin_bit_cast(s16x8, hbl0),
            lacc0, 0, 0, 0);
        lacc1 = __builtin_amdgcn_mfma_f32_16x16x32_bf16(
            __builtin_bit_cast(s16x8, a1), __builtin_bit_cast(s16x8, hbl1),
            lacc1, 0, 0, 0);
      }
      if (owner) {
        f32x4 lg = lacc0 + lacc1;
        float4 o;
        o.x = lg[0] + bfcv.x;
        o.y = lg[1] + bfcv.y;
        o.z = lg[2] + bfcv.z;
        o.w = lg[3] + bfcv.w;
        *(float4*)(lout_base + (size_t)(t - 1) * 768) = o;
      }
    }
  }
}

extern "C" void kernel_launch(void* const* d_in, const int* in_sizes, int n_in,
                              void* d_out, int out_size, void* d_ws,
                              size_t ws_size, hipStream_t stream) {
  const float* hidden = (const float*)d_in[0];
  const float* x = (const float*)d_in[1];
  const float* W_ih = (const float*)d_in[2];
  const float* W_hh = (const float*)d_in[3];
  const float* b_ih = (const float*)d_in[4];
  const float* b_hh = (const float*)d_in[5];
  const float* W_fc = (const float*)d_in[6];
  const float* b_fc = (const float*)d_in[7];
  float* out = (float*)d_out;
  float* xp = out;  // xp [B*S][768] fp32; each row is consumed at step s and
                    // overwritten by the fused logits row at step s+1

  char* ws = (char*)d_ws;
  unsigned short* hseq = (unsigned short*)ws;  // [(S+1)][B][H] bf16
  size_t hseq_elems = (size_t)(S_ + 1) * B_ * H_;
  unsigned short* wih_b = hseq + hseq_elems;
  unsigned short* wfc_b = wih_b + 768 * 768;

  // zero h[1..S]: required every launch (data-as-flag poll; ws is not
  // re-poisoned between replays)
  (void)hipMemsetAsync(hseq + (size_t)B_ * H_, 0, (size_t)S_ * B_ * H_ * 2,
                       stream);
  conv_f2b_kernel<<<576, 256, 0, stream>>>(W_ih, wih_b, 768 * 768);
  conv_f2b_kernel<<<576, 256, 0, stream>>>(W_fc, wfc_b, 768 * 768);
  conv_f2b_kernel<<<48, 256, 0, stream>>>(hidden, hseq, B_ * H_);
  dim3 grid(512, 6);
  gemm_kernel<0><<<grid, 256, 0, stream>>>(x, wih_b, xp, b_ih, b_hh);
  scan_kernel<<<GB * CB, 512, 0, stream>>>(W_hh, xp, hseq, wfc_b, b_fc, out);
  tail_kernel<<<192, 256, 0, stream>>>(hseq + (size_t)S_ * B_ * H_,
                                       out + (size_t)65536 * 768, B_ * H_);
}

// Round 16
// 4488.537 us; speedup vs baseline: 1.7529x; 1.7529x over previous
//
#include <hip/hip_runtime.h>

#define B_ 64
#define S_ 1024
#define H_ 768
#define GB 8    // batch groups (8 rows each)
#define CB 6    // col-blocks per group (128 cols each)

typedef short s16x8 __attribute__((ext_vector_type(8)));
typedef float f32x4 __attribute__((ext_vector_type(4)));
typedef unsigned u32x4 __attribute__((ext_vector_type(4)));

__device__ __forceinline__ unsigned short f2b(float f) {
  unsigned u = __builtin_bit_cast(unsigned, f);
  u += 0x7FFFu + ((u >> 16) & 1u);
  return (unsigned short)(u >> 16);
}
__device__ __forceinline__ float b2f(unsigned short h) {
  unsigned u = ((unsigned)h) << 16;
  return __builtin_bit_cast(float, u);
}

// tanh(x) = 1 - 2/(1+e^{2x}); exact at +-inf, ~1e-7 rel err, no branches.
__device__ __forceinline__ float fast_tanh(float x) {
  float e = __builtin_amdgcn_exp2f(x * 2.8853900817779268f);  // e^{2x}
  return 1.0f - 2.0f * __builtin_amdgcn_rcpf(1.0f + e);
}

__global__ void conv_f2b_kernel(const float* __restrict__ src,
                                unsigned short* __restrict__ dst, int n) {
  int i = (blockIdx.x * blockDim.x + threadIdx.x) * 4;
  if (i >= n) return;
  float4 v = *(const float4*)(src + i);
  unsigned long long p = (unsigned long long)f2b(v.x)
      | ((unsigned long long)f2b(v.y) << 16)
      | ((unsigned long long)f2b(v.z) << 32)
      | ((unsigned long long)f2b(v.w) << 48);
  *(unsigned long long*)(dst + i) = p;
}

__global__ void tail_kernel(const unsigned short* __restrict__ src,
                            float* __restrict__ dst, int n) {
  int i = blockIdx.x * blockDim.x + threadIdx.x;
  if (i < n) dst[i] = b2f(src[i]);
}

// xp GEMM: C[r][n] = sum_k x[r][k] * W_ih[n][k] + b_ih[n] + b_hh[n].
__global__ __launch_bounds__(256) void gemm_kernel(
    const float* __restrict__ Aptr, const unsigned short* __restrict__ Bw,
    float* __restrict__ C, const float* __restrict__ bias1,
    const float* __restrict__ bias2) {
  __shared__ unsigned short As[128 * 64];
  __shared__ unsigned short Bs[128 * 64];
  const int tid = threadIdx.x;
  const int l = tid & 63;
  const int w = tid >> 6;
  const int wm = w >> 1, wn = w & 1;
  const int r0 = blockIdx.x * 128;
  const int n0 = blockIdx.y * 128;
  const int row16 = l & 15;
  const int g4 = l >> 4;
  const int swz = (l & 7) << 3;

  const int srow = tid >> 1;
  const int shalf = (tid & 1) * 32;
  size_t a_off = (size_t)(r0 + srow) * 768;
  const size_t b_off = (size_t)(n0 + srow) * 768;
  const int swrow = (srow & 7) << 3;

  f32x4 acc[4][4] = {};

  for (int k0 = 0; k0 < 768; k0 += 64) {
    {
      const float* Af = Aptr + a_off + k0 + shalf;
#pragma unroll
      for (int jj = 0; jj < 4; ++jj) {
        float4 v0 = *(const float4*)(Af + jj * 8);
        float4 v1 = *(const float4*)(Af + jj * 8 + 4);
        uint4 p;
        p.x = f2b(v0.x) | ((unsigned)f2b(v0.y) << 16);
        p.y = f2b(v0.z) | ((unsigned)f2b(v0.w) << 16);
        p.z = f2b(v1.x) | ((unsigned)f2b(v1.y) << 16);
        p.w = f2b(v1.z) | ((unsigned)f2b(v1.w) << 16);
        int c = (shalf + jj * 8) ^ swrow;
        *(uint4*)(As + srow * 64 + c) = p;
      }
    }
    {
      const unsigned short* Bb = Bw + b_off + k0 + shalf;
#pragma unroll
      for (int jj = 0; jj < 4; ++jj) {
        uint4 p = *(const uint4*)(Bb + jj * 8);
        int c = (shalf + jj * 8) ^ swrow;
        *(uint4*)(Bs + srow * 64 + c) = p;
      }
    }
    __syncthreads();
#pragma unroll
    for (int kb = 0; kb < 2; ++kb) {
      int ccol = (kb * 32 + g4 * 8) ^ swz;
      s16x8 af[4], bfr[4];
#pragma unroll
      for (int mi = 0; mi < 4; ++mi)
        af[mi] = __builtin_bit_cast(
            s16x8, *(const uint4*)(As + (wm * 64 + mi * 16 + row16) * 64 + ccol));
#pragma unroll
      for (int ni = 0; ni < 4; ++ni)
        bfr[ni] = __builtin_bit_cast(
            s16x8, *(const uint4*)(Bs + (wn * 64 + ni * 16 + row16) * 64 + ccol));
#pragma unroll
      for (int mi = 0; mi < 4; ++mi)
#pragma unroll
        for (int ni = 0; ni < 4; ++ni)
          acc[mi][ni] = __builtin_amdgcn_mfma_f32_16x16x32_bf16(
              af[mi], bfr[ni], acc[mi][ni], 0, 0, 0);
    }
    __syncthreads();
  }
#pragma unroll
  for (int ni = 0; ni < 4; ++ni) {
    int col = n0 + wn * 64 + ni * 16 + row16;
    float bv = bias1[col] + bias2[col];
#pragma unroll
    for (int mi = 0; mi < 4; ++mi) {
      int rbase = r0 + wm * 64 + mi * 16 + g4 * 4;
#pragma unroll
      for (int i = 0; i < 4; ++i)
        C[(size_t)(rbase + i) * 768 + col] = acc[mi][ni][i] + bv;
    }
  }
}

// Persistent recurrence + fused logits (R16): 48 blocks = 8 batch-groups x
// 6 col-blocks, 512 threads.  Protocol = R14 proven (data-as-flag sc1/IF,
// zero-sentinel, memset-zeroed slab, self-staged own cols, paired 16B
// stores, 16-slot read swizzle w/ don't-care lanes).  R16 vs R15: W_fc
// fragments live in REGISTERS (preloaded once, like W_hh) and the logits
// MFMA shares the SAME LDS B-fragment as the h-update MFMA in one unified
// kb-loop — zero global loads in the steady-state loop (R15 streamed W_fc
// from memory: 12 dependent round-trips/step = +5.3us/step stall).
// Register budget: only 48 CUs are occupied (1 block/CU, 2 waves/SIMD) so
// the VGPR cap is 256; launch_bounds(512,2) grants it.  wfrag 96 + wfcfrag
// 96 + hb 8 + accs 24 + misc ~= 235.
__global__ __launch_bounds__(512, 2) void scan_kernel(
    const float* __restrict__ W_hh, const float* __restrict__ xp,
    unsigned short* __restrict__ hseq, const unsigned short* __restrict__ wfc,
    const float* __restrict__ b_fc, float* __restrict__ out) {
  __shared__ unsigned short hs[2][8 * 768];  // 2 x 12KB
  const int tid = threadIdx.x;
  const int l = tid & 63;
  const int w = tid >> 6;
  const int bg = blockIdx.x / CB;  // 0..7
  const int cb = blockIdx.x % CB;  // 0..5
  const int b0 = bg * 8;
  const int c0 = cb * 128;
  const int row16 = l & 15;
  const int row8 = row16 & 7;
  const int g4 = l >> 4;

  // pack W_hh fragments: A[row=l&15 (out col)][k = kb*32 + (l>>4)*8 + j]
  uint4 wfrag[24];
  {
    const float* wr = W_hh + (size_t)(c0 + w * 16 + row16) * 768;
#pragma unroll
    for (int kb = 0; kb < 24; ++kb) {
      int k0 = kb * 32 + g4 * 8;
      float4 v0 = *(const float4*)(wr + k0);
      float4 v1 = *(const float4*)(wr + k0 + 4);
      uint4 p;
      p.x = f2b(v0.x) | ((unsigned)f2b(v0.y) << 16);
      p.y = f2b(v0.z) | ((unsigned)f2b(v0.w) << 16);
      p.z = f2b(v1.x) | ((unsigned)f2b(v1.y) << 16);
      p.w = f2b(v1.z) | ((unsigned)f2b(v1.w) << 16);
      wfrag[kb] = p;
    }
  }
  // preload W_fc fragments (already bf16): same layout as wfrag
  uint4 wfcfrag[24];
  {
    const unsigned short* wr = wfc + (size_t)(c0 + w * 16 + row16) * 768;
#pragma unroll
    for (int kb = 0; kb < 24; ++kb)
      wfcfrag[kb] = *(const uint4*)(wr + kb * 32 + g4 * 8);
  }

  // foreign-chunk geometry (t>=1): 80 foreign 16B chunks/row x 8 rows = 640
  const int c08 = cb * 16;
  const int nch = (tid < 128) ? 2 : 1;
  size_t gF[2];
  int lF[2];
#pragma unroll
  for (int j = 0; j < 2; ++j) {
    int fi = (j == 0) ? tid : (512 + (tid & 127));
    int row = fi / 80;
    int f = fi - row * 80;
    int col8 = f + (f >= c08 ? 16 : 0);
    gF[j] = (size_t)(b0 + row) * 768 + col8 * 8;
    lF[j] = row * 1536 + ((col8 * 16) ^ ((row & 7) << 4));
  }

  const size_t hcol = c0 + w * 16 + g4 * 4;
  unsigned short* hout_base = hseq + (size_t)(b0 + row8) * 768 + hcol;
  const float* xp_base = xp + (size_t)(b0 + row8) * 1024 * 768 + hcol;
  const int soff = row8 * 1536 + (((int)hcol * 2) ^ (row8 << 4));
  const int rswz = row16 << 4;  // 16-slot key; row16>=8 reads don't-care data
  const bool owner = (row16 < 8);

  const float4 bfcv = *(const float4*)(b_fc + hcol);
  float* lout_base = out + (size_t)(b0 + row8) * 1024 * 768 + hcol;

  for (int t = 0; t <= S_; ++t) {
    char* lb = (char*)hs[t & 1];
    float4 xpv = {0.f, 0.f, 0.f, 0.f};
    if (t < S_) xpv = *(const float4*)(xp_base + (size_t)t * 768);
    const unsigned short* hin = hseq + (size_t)t * (B_ * H_);
    if (t == 0) {
      // h0 (= zeros) pre-written by conv kernel; full slab = 768 chunks.
      uint4 cv0[2];
      int nj = (tid < 256) ? 2 : 1;
#pragma unroll
      for (int j = 0; j < 2; ++j) {
        if (j < nj) {
          int ch = (j == 0) ? tid : (512 + (tid & 255));
          int row = ch / 96;
          int col8 = ch - row * 96;
          asm volatile("global_load_dwordx4 %0, %1, off sc1"
                       : "=&v"(cv0[j])
                       : "v"(hin + (size_t)(b0 + row) * 768 + col8 * 8));
        }
      }
      asm volatile("s_waitcnt vmcnt(0)" ::: "memory");
      __builtin_amdgcn_sched_barrier(0);
#pragma unroll
      for (int j = 0; j < 2; ++j) {
        if (j < nj) {
          int ch = (j == 0) ? tid : (512 + (tid & 255));
          int row = ch / 96;
          int col8 = ch - row * 96;
          *(uint4*)(lb + row * 1536 + ((col8 * 16) ^ ((row & 7) << 4))) =
              cv0[j];
        }
      }
    } else {
      uint4 cv[2];
      unsigned done = 0;
      const unsigned full = (nch == 2) ? 3u : 1u;
      while (done != full) {
        if (!(done & 1))
          asm volatile("global_load_dwordx4 %0, %1, off sc1"
                       : "=&v"(cv[0]) : "v"(hin + gF[0]));
        if (nch == 2 && !(done & 2))
          asm volatile("global_load_dwordx4 %0, %1, off sc1"
                       : "=&v"(cv[1]) : "v"(hin + gF[1]));
        asm volatile("s_waitcnt vmcnt(0)" ::: "memory");
        __builtin_amdgcn_sched_barrier(0);  // keep checks after the waitcnt
        if (!(done & 1) && (cv[0].x | cv[0].y) != 0 && (cv[0].z | cv[0].w) != 0) {
          done |= 1;
          *(uint4*)(lb + lF[0]) = cv[0];
        }
        if (nch == 2 && !(done & 2) && (cv[1].x | cv[1].y) != 0 &&
            (cv[1].z | cv[1].w) != 0) {
          done |= 2;
          *(uint4*)(lb + lF[1]) = cv[1];
        }
      }
    }
    __syncthreads();

    // unified MFMA loop: one LDS B-fragment feeds BOTH the h-update and the
    // logits MFMA (same h(t) operand).  2 chains each to cap live registers.
    const char* rb = lb + row8 * 1536;
    f32x4 acc0 = {xpv.x, xpv.y, xpv.z, xpv.w};
    f32x4 acc1 = {0.f, 0.f, 0.f, 0.f};
    f32x4 lac0 = {0.f, 0.f, 0.f, 0.f};
    f32x4 lac1 = {0.f, 0.f, 0.f, 0.f};
#pragma unroll
    for (int kb = 0; kb < 24; kb += 2) {
      uint4 h0 = *(const uint4*)(rb + ((kb * 64 + g4 * 16) ^ rswz));
      uint4 h1 = *(const uint4*)(rb + (((kb + 1) * 64 + g4 * 16) ^ rswz));
      acc0 = __builtin_amdgcn_mfma_f32_16x16x32_bf16(
          __builtin_bit_cast(s16x8, wfrag[kb]), __builtin_bit_cast(s16x8, h0),
          acc0, 0, 0, 0);
      lac0 = __builtin_amdgcn_mfma_f32_16x16x32_bf16(
          __builtin_bit_cast(s16x8, wfcfrag[kb]),
          __builtin_bit_cast(s16x8, h0), lac0, 0, 0, 0);
      acc1 = __builtin_amdgcn_mfma_f32_16x16x32_bf16(
          __builtin_bit_cast(s16x8, wfrag[kb + 1]),
          __builtin_bit_cast(s16x8, h1), acc1, 0, 0, 0);
      lac1 = __builtin_amdgcn_mfma_f32_16x16x32_bf16(
          __builtin_bit_cast(s16x8, wfcfrag[kb + 1]),
          __builtin_bit_cast(s16x8, h1), lac1, 0, 0, 0);
    }

    if (t < S_) {
      f32x4 g = acc0 + acc1;
      float t0 = fast_tanh(g[0]), t1 = fast_tanh(g[1]);
      float t2 = fast_tanh(g[2]), t3 = fast_tanh(g[3]);
      unsigned long long pk = (unsigned long long)f2b(t0)
          | ((unsigned long long)f2b(t1) << 16)
          | ((unsigned long long)f2b(t2) << 32)
          | ((unsigned long long)f2b(t3) << 48);
      if (pk == 0) pk = 1;  // readiness sentinel

      // self-stage own cols for step t+1 (single writer; rows 0..7 only)
      if (owner) *(unsigned long long*)((char*)hs[(t + 1) & 1] + soff) = pk;

      // paired 16B global store (lanes l, l^16; even-g4 owner lane stores)
      unsigned long long po = __shfl(pk, l ^ 16);
      if (owner && (g4 & 1) == 0) {
        u32x4 st;
        st[0] = (unsigned)pk;
        st[1] = (unsigned)(pk >> 32);
        st[2] = (unsigned)po;
        st[3] = (unsigned)(po >> 32);
        asm volatile("global_store_dwordx4 %0, %1, off sc1" ::"v"(
                         hout_base + (size_t)(t + 1) * (B_ * H_)),
                     "v"(st)
                     : "memory");
      }
    }

    // logits row s = t-1 (uses h(t), already consumed above)
    if (t >= 1 && owner) {
      f32x4 lg = lac0 + lac1;
      float4 o;
      o.x = lg[0] + bfcv.x;
      o.y = lg[1] + bfcv.y;
      o.z = lg[2] + bfcv.z;
      o.w = lg[3] + bfcv.w;
      *(float4*)(lout_base + (size_t)(t - 1) * 768) = o;
    }
  }
}

extern "C" void kernel_launch(void* const* d_in, const int* in_sizes, int n_in,
                              void* d_out, int out_size, void* d_ws,
                              size_t ws_size, hipStream_t stream) {
  const float* hidden = (const float*)d_in[0];
  const float* x = (const float*)d_in[1];
  const float* W_ih = (const float*)d_in[2];
  const float* W_hh = (const float*)d_in[3];
  const float* b_ih = (const float*)d_in[4];
  const float* b_hh = (const float*)d_in[5];
  const float* W_fc = (const float*)d_in[6];
  const float* b_fc = (const float*)d_in[7];
  float* out = (float*)d_out;
  float* xp = out;  // xp [B*S][768] fp32; row (b,s) is consumed at step s and
                    // overwritten by the fused logits row at step s+1

  char* ws = (char*)d_ws;
  unsigned short* hseq = (unsigned short*)ws;  // [(S+1)][B][H] bf16
  size_t hseq_elems = (size_t)(S_ + 1) * B_ * H_;
  unsigned short* wih_b = hseq + hseq_elems;
  unsigned short* wfc_b = wih_b + 768 * 768;

  // zero h[1..S]: required every launch (data-as-flag poll; ws is not
  // re-poisoned between replays)
  (void)hipMemsetAsync(hseq + (size_t)B_ * H_, 0, (size_t)S_ * B_ * H_ * 2,
                       stream);
  conv_f2b_kernel<<<576, 256, 0, stream>>>(W_ih, wih_b, 768 * 768);
  conv_f2b_kernel<<<576, 256, 0, stream>>>(W_fc, wfc_b, 768 * 768);
  conv_f2b_kernel<<<48, 256, 0, stream>>>(hidden, hseq, B_ * H_);
  dim3 grid(512, 6);
  gemm_kernel<<<grid, 256, 0, stream>>>(x, wih_b, xp, b_ih, b_hh);
  scan_kernel<<<GB * CB, 512, 0, stream>>>(W_hh, xp, hseq, wfc_b, b_fc, out);
  tail_kernel<<<192, 256, 0, stream>>>(hseq + (size_t)S_ * B_ * H_,
                                       out + (size_t)65536 * 768, B_ * H_);
}

// Round 17
// 2732.039 us; speedup vs baseline: 2.8798x; 1.6429x over previous
//
#include <hip/hip_runtime.h>

#define B_ 64
#define S_ 1024
#define H_ 768
#define GB 8    // batch groups (8 rows each)
#define CB 6    // col-blocks per group (128 cols each)

typedef short s16x8 __attribute__((ext_vector_type(8)));
typedef float f32x4 __attribute__((ext_vector_type(4)));
typedef unsigned u32x4 __attribute__((ext_vector_type(4)));

__device__ __forceinline__ unsigned short f2b(float f) {
  unsigned u = __builtin_bit_cast(unsigned, f);
  u += 0x7FFFu + ((u >> 16) & 1u);
  return (unsigned short)(u >> 16);
}
__device__ __forceinline__ float b2f(unsigned short h) {
  unsigned u = ((unsigned)h) << 16;
  return __builtin_bit_cast(float, u);
}

// tanh(x) = 1 - 2/(1+e^{2x}); exact at +-inf, ~1e-7 rel err, no branches.
__device__ __forceinline__ float fast_tanh(float x) {
  float e = __builtin_amdgcn_exp2f(x * 2.8853900817779268f);  // e^{2x}
  return 1.0f - 2.0f * __builtin_amdgcn_rcpf(1.0f + e);
}

__global__ void conv_f2b_kernel(const float* __restrict__ src,
                                unsigned short* __restrict__ dst, int n) {
  int i = (blockIdx.x * blockDim.x + threadIdx.x) * 4;
  if (i >= n) return;
  float4 v = *(const float4*)(src + i);
  unsigned long long p = (unsigned long long)f2b(v.x)
      | ((unsigned long long)f2b(v.y) << 16)
      | ((unsigned long long)f2b(v.z) << 32)
      | ((unsigned long long)f2b(v.w) << 48);
  *(unsigned long long*)(dst + i) = p;
}

// GEMM with on-the-fly fp32->bf16 conversion of BOTH operands' staging
// (no pre-converted weight buffers -> two conv launches eliminated).
// MODE0: A = x (fp32), bias = b_ih + b_hh, C = xp.
// MODE1: A = hseq (bf16, row-gathered r=b*1024+s -> hseq[(s+1)*64+b]),
//        bias = b_fc; block (0,0) additionally writes the final-hidden
//        floats (tail fold — hseq[S] is complete by kernel ordering).
template <int MODE>
__global__ __launch_bounds__(256) void gemm_kernel(
    const void* __restrict__ Aptr, const float* __restrict__ Bw,
    float* __restrict__ C, const float* __restrict__ bias1,
    const float* __restrict__ bias2, const unsigned short* __restrict__ hfin,
    float* __restrict__ hfin_out) {
  __shared__ unsigned short As[128 * 64];
  __shared__ unsigned short Bs[128 * 64];
  const int tid = threadIdx.x;
  const int l = tid & 63;
  const int w = tid >> 6;
  const int wm = w >> 1, wn = w & 1;
  const int r0 = blockIdx.x * 128;
  const int n0 = blockIdx.y * 128;
  const int row16 = l & 15;
  const int g4 = l >> 4;
  const int swz = (l & 7) << 3;

  const int srow = tid >> 1;
  const int shalf = (tid & 1) * 32;
  size_t a_off;
  if (MODE == 0) {
    a_off = (size_t)(r0 + srow) * 768;
  } else {
    int ar = r0 + srow;
    a_off = ((size_t)((ar & 1023) + 1) * 64 + (ar >> 10)) * 768;
  }
  const size_t b_off = (size_t)(n0 + srow) * 768;
  const int swrow = (srow & 7) << 3;

  f32x4 acc[4][4] = {};

  for (int k0 = 0; k0 < 768; k0 += 64) {
    if (MODE == 0) {
      const float* Af = (const float*)Aptr + a_off + k0 + shalf;
#pragma unroll
      for (int jj = 0; jj < 4; ++jj) {
        float4 v0 = *(const float4*)(Af + jj * 8);
        float4 v1 = *(const float4*)(Af + jj * 8 + 4);
        uint4 p;
        p.x = f2b(v0.x) | ((unsigned)f2b(v0.y) << 16);
        p.y = f2b(v0.z) | ((unsigned)f2b(v0.w) << 16);
        p.z = f2b(v1.x) | ((unsigned)f2b(v1.y) << 16);
        p.w = f2b(v1.z) | ((unsigned)f2b(v1.w) << 16);
        int c = (shalf + jj * 8) ^ swrow;
        *(uint4*)(As + srow * 64 + c) = p;
      }
    } else {
      const unsigned short* Ab = (const unsigned short*)Aptr + a_off + k0 + shalf;
#pragma unroll
      for (int jj = 0; jj < 4; ++jj) {
        uint4 p = *(const uint4*)(Ab + jj * 8);
        int c = (shalf + jj * 8) ^ swrow;
        *(uint4*)(As + srow * 64 + c) = p;
      }
    }
    {
      const float* Bf = Bw + b_off + k0 + shalf;
#pragma unroll
      for (int jj = 0; jj < 4; ++jj) {
        float4 v0 = *(const float4*)(Bf + jj * 8);
        float4 v1 = *(const float4*)(Bf + jj * 8 + 4);
        uint4 p;
        p.x = f2b(v0.x) | ((unsigned)f2b(v0.y) << 16);
        p.y = f2b(v0.z) | ((unsigned)f2b(v0.w) << 16);
        p.z = f2b(v1.x) | ((unsigned)f2b(v1.y) << 16);
        p.w = f2b(v1.z) | ((unsigned)f2b(v1.w) << 16);
        int c = (shalf + jj * 8) ^ swrow;
        *(uint4*)(Bs + srow * 64 + c) = p;
      }
    }
    __syncthreads();
#pragma unroll
    for (int kb = 0; kb < 2; ++kb) {
      int ccol = (kb * 32 + g4 * 8) ^ swz;
      s16x8 af[4], bfr[4];
#pragma unroll
      for (int mi = 0; mi < 4; ++mi)
        af[mi] = __builtin_bit_cast(
            s16x8, *(const uint4*)(As + (wm * 64 + mi * 16 + row16) * 64 + ccol));
#pragma unroll
      for (int ni = 0; ni < 4; ++ni)
        bfr[ni] = __builtin_bit_cast(
            s16x8, *(const uint4*)(Bs + (wn * 64 + ni * 16 + row16) * 64 + ccol));
#pragma unroll
      for (int mi = 0; mi < 4; ++mi)
#pragma unroll
        for (int ni = 0; ni < 4; ++ni)
          acc[mi][ni] = __builtin_amdgcn_mfma_f32_16x16x32_bf16(
              af[mi], bfr[ni], acc[mi][ni], 0, 0, 0);
    }
    __syncthreads();
  }
#pragma unroll
  for (int ni = 0; ni < 4; ++ni) {
    int col = n0 + wn * 64 + ni * 16 + row16;
    float bv = bias1[col] + (MODE == 0 ? bias2[col] : 0.0f);
#pragma unroll
    for (int mi = 0; mi < 4; ++mi) {
      int rbase = r0 + wm * 64 + mi * 16 + g4 * 4;
#pragma unroll
      for (int i = 0; i < 4; ++i)
        C[(size_t)(rbase + i) * 768 + col] = acc[mi][ni][i] + bv;
    }
  }
  // tail fold: final hidden bf16 -> f32 (one block only; 192 elems/thread)
  if (MODE == 1 && blockIdx.x == 0 && blockIdx.y == 0) {
    for (int i = tid; i < B_ * H_; i += 256) hfin_out[i] = b2f(hfin[i]);
  }
}

// Persistent recurrence (R17 = R14 exact): 48 blocks = 8 batch-groups
// (8 rows) x 6 col-blocks (128 cols), 512 threads.  Data-as-flag protocol
// (sc1/IF, zero-sentinel, memset-zeroed slab, self-staged own cols, paired
// 16B stores); 16-slot read swizzle with don't-care lanes (row16>=8 lanes
// read garbage that only reaches unstored MFMA cols — bank-conflict-free).
// Probed floor: ~2.06us/step = 1024 serial cross-XCD store->IF->poll RTs;
// compute is ~6% of the step.  Fusion attempts (R15 stream / R16 regs) both
// regress: W_hh + W_fc cannot be co-resident under the 256-reg unified file.
__global__ __launch_bounds__(512) void scan_kernel(
    const float* __restrict__ W_hh, const float* __restrict__ xp,
    unsigned short* __restrict__ hseq) {
  __shared__ unsigned short hs[2][8 * 768];  // 2 x 12KB
  const int tid = threadIdx.x;
  const int l = tid & 63;
  const int w = tid >> 6;
  const int bg = blockIdx.x / CB;  // 0..7
  const int cb = blockIdx.x % CB;  // 0..5
  const int b0 = bg * 8;
  const int c0 = cb * 128;
  const int row16 = l & 15;
  const int row8 = row16 & 7;
  const int g4 = l >> 4;

  // pack W_hh fragments: A[row=l&15 (out col)][k = kb*32 + (l>>4)*8 + j]
  uint4 wfrag[24];
  {
    const float* wr = W_hh + (size_t)(c0 + w * 16 + row16) * 768;
#pragma unroll
    for (int kb = 0; kb < 24; ++kb) {
      int k0 = kb * 32 + g4 * 8;
      float4 v0 = *(const float4*)(wr + k0);
      float4 v1 = *(const float4*)(wr + k0 + 4);
      uint4 p;
      p.x = f2b(v0.x) | ((unsigned)f2b(v0.y) << 16);
      p.y = f2b(v0.z) | ((unsigned)f2b(v0.w) << 16);
      p.z = f2b(v1.x) | ((unsigned)f2b(v1.y) << 16);
      p.w = f2b(v1.z) | ((unsigned)f2b(v1.w) << 16);
      wfrag[kb] = p;
    }
  }

  // foreign-chunk geometry (t>=1): 80 foreign 16B chunks/row x 8 rows = 640
  const int c08 = cb * 16;
  const int nch = (tid < 128) ? 2 : 1;
  size_t gF[2];
  int lF[2];
#pragma unroll
  for (int j = 0; j < 2; ++j) {
    int fi = (j == 0) ? tid : (512 + (tid & 127));
    int row = fi / 80;
    int f = fi - row * 80;
    int col8 = f + (f >= c08 ? 16 : 0);
    gF[j] = (size_t)(b0 + row) * 768 + col8 * 8;
    lF[j] = row * 1536 + ((col8 * 16) ^ ((row & 7) << 4));
  }

  const size_t hcol = c0 + w * 16 + g4 * 4;
  unsigned short* hout_base = hseq + (size_t)(b0 + row8) * 768 + hcol;
  const float* xp_base = xp + (size_t)(b0 + row8) * 1024 * 768 + hcol;
  const int soff = row8 * 1536 + (((int)hcol * 2) ^ (row8 << 4));
  const int rswz = row16 << 4;  // 16-slot key; row16>=8 reads don't-care data
  const bool owner = (row16 < 8);

  for (int t = 0; t < S_; ++t) {
    char* lb = (char*)hs[t & 1];
    float4 xpv = *(const float4*)(xp_base + (size_t)t * 768);  // off crit path
    const unsigned short* hin = hseq + (size_t)t * (B_ * H_);
    if (t == 0) {
      // h0 pre-written by conv kernel; full slab = 768 chunks.
      uint4 cv0[2];
      int nj = (tid < 256) ? 2 : 1;
#pragma unroll
      for (int j = 0; j < 2; ++j) {
        if (j < nj) {
          int ch = (j == 0) ? tid : (512 + (tid & 255));
          int row = ch / 96;
          int col8 = ch - row * 96;
          asm volatile("global_load_dwordx4 %0, %1, off sc1"
                       : "=&v"(cv0[j])
                       : "v"(hin + (size_t)(b0 + row) * 768 + col8 * 8));
        }
      }
      asm volatile("s_waitcnt vmcnt(0)" ::: "memory");
      __builtin_amdgcn_sched_barrier(0);
#pragma unroll
      for (int j = 0; j < 2; ++j) {
        if (j < nj) {
          int ch = (j == 0) ? tid : (512 + (tid & 255));
          int row = ch / 96;
          int col8 = ch - row * 96;
          *(uint4*)(lb + row * 1536 + ((col8 * 16) ^ ((row & 7) << 4))) =
              cv0[j];
        }
      }
    } else {
      uint4 cv[2];
      unsigned done = 0;
      const unsigned full = (nch == 2) ? 3u : 1u;
      while (done != full) {
        if (!(done & 1))
          asm volatile("global_load_dwordx4 %0, %1, off sc1"
                       : "=&v"(cv[0]) : "v"(hin + gF[0]));
        if (nch == 2 && !(done & 2))
          asm volatile("global_load_dwordx4 %0, %1, off sc1"
                       : "=&v"(cv[1]) : "v"(hin + gF[1]));
        asm volatile("s_waitcnt vmcnt(0)" ::: "memory");
        __builtin_amdgcn_sched_barrier(0);  // keep checks after the waitcnt
        if (!(done & 1) && (cv[0].x | cv[0].y) != 0 && (cv[0].z | cv[0].w) != 0) {
          done |= 1;
          *(uint4*)(lb + lF[0]) = cv[0];
        }
        if (nch == 2 && !(done & 2) && (cv[1].x | cv[1].y) != 0 &&
            (cv[1].z | cv[1].w) != 0) {
          done |= 2;
          *(uint4*)(lb + lF[1]) = cv[1];
        }
      }
    }
    __syncthreads();

    uint4 hb[24];
    const char* rb = lb + row8 * 1536;
#pragma unroll
    for (int kb = 0; kb < 24; ++kb)
      hb[kb] = *(const uint4*)(rb + ((kb * 64 + g4 * 16) ^ rswz));

    f32x4 acc0 = {xpv.x, xpv.y, xpv.z, xpv.w};
    f32x4 acc1 = {0.f, 0.f, 0.f, 0.f};
    f32x4 acc2 = {0.f, 0.f, 0.f, 0.f};
    f32x4 acc3 = {0.f, 0.f, 0.f, 0.f};
#pragma unroll
    for (int kb = 0; kb < 24; kb += 4) {
      acc0 = __builtin_amdgcn_mfma_f32_16x16x32_bf16(
          __builtin_bit_cast(s16x8, wfrag[kb]),
          __builtin_bit_cast(s16x8, hb[kb]), acc0, 0, 0, 0);
      acc1 = __builtin_amdgcn_mfma_f32_16x16x32_bf16(
          __builtin_bit_cast(s16x8, wfrag[kb + 1]),
          __builtin_bit_cast(s16x8, hb[kb + 1]), acc1, 0, 0, 0);
      acc2 = __builtin_amdgcn_mfma_f32_16x16x32_bf16(
          __builtin_bit_cast(s16x8, wfrag[kb + 2]),
          __builtin_bit_cast(s16x8, hb[kb + 2]), acc2, 0, 0, 0);
      acc3 = __builtin_amdgcn_mfma_f32_16x16x32_bf16(
          __builtin_bit_cast(s16x8, wfrag[kb + 3]),
          __builtin_bit_cast(s16x8, hb[kb + 3]), acc3, 0, 0, 0);
    }
    f32x4 g = (acc0 + acc1) + (acc2 + acc3);
    float t0 = fast_tanh(g[0]), t1 = fast_tanh(g[1]);
    float t2 = fast_tanh(g[2]), t3 = fast_tanh(g[3]);
    unsigned long long pk = (unsigned long long)f2b(t0)
        | ((unsigned long long)f2b(t1) << 16)
        | ((unsigned long long)f2b(t2) << 32)
        | ((unsigned long long)f2b(t3) << 48);
    if (pk == 0) pk = 1;  // readiness sentinel: never store an all-zero word

    // self-stage own cols for step t+1 (single writer; rows 0..7 only)
    if (owner) *(unsigned long long*)((char*)hs[(t + 1) & 1] + soff) = pk;

    // paired 16B global store: lanes (l, l^16) -> even-g4 owner lane stores
    unsigned long long po = __shfl(pk, l ^ 16);
    if (owner && (g4 & 1) == 0) {
      u32x4 st;
      st[0] = (unsigned)pk;
      st[1] = (unsigned)(pk >> 32);
      st[2] = (unsigned)po;
      st[3] = (unsigned)(po >> 32);
      asm volatile("global_store_dwordx4 %0, %1, off sc1" ::"v"(
                       hout_base + (size_t)(t + 1) * (B_ * H_)),
                   "v"(st)
                   : "memory");
    }
    // no trailing barrier: double-buffered LDS; lap-safety via the
    // cross-block store->poll dependency chain (see R13 note).
  }
}

extern "C" void kernel_launch(void* const* d_in, const int* in_sizes, int n_in,
                              void* d_out, int out_size, void* d_ws,
                              size_t ws_size, hipStream_t stream) {
  const float* hidden = (const float*)d_in[0];
  const float* x = (const float*)d_in[1];
  const float* W_ih = (const float*)d_in[2];
  const float* W_hh = (const float*)d_in[3];
  const float* b_ih = (const float*)d_in[4];
  const float* b_hh = (const float*)d_in[5];
  const float* W_fc = (const float*)d_in[6];
  const float* b_fc = (const float*)d_in[7];
  float* out = (float*)d_out;
  float* xp = out;  // xp [B*S][768] fp32 reuses the logits region

  char* ws = (char*)d_ws;
  unsigned short* hseq = (unsigned short*)ws;  // [(S+1)][B][H] bf16

  // zero h[1..S]: required every launch (data-as-flag poll; ws is not
  // re-poisoned between replays)
  (void)hipMemsetAsync(hseq + (size_t)B_ * H_, 0, (size_t)S_ * B_ * H_ * 2,
                       stream);
  conv_f2b_kernel<<<48, 256, 0, stream>>>(hidden, hseq, B_ * H_);
  dim3 grid(512, 6);
  gemm_kernel<0><<<grid, 256, 0, stream>>>(x, W_ih, xp, b_ih, b_hh, nullptr,
                                           nullptr);
  scan_kernel<<<GB * CB, 512, 0, stream>>>(W_hh, xp, hseq);
  gemm_kernel<1><<<grid, 256, 0, stream>>>(hseq, W_fc, out, b_fc, nullptr,
                                           hseq + (size_t)S_ * B_ * H_,
                                           out + (size_t)65536 * 768);
}

// Round 18
// 2571.226 us; speedup vs baseline: 3.0599x; 1.0625x over previous
//
#include <hip/hip_runtime.h>

#define B_ 64
#define S_ 1024
#define H_ 768
#define GB 8    // batch groups (8 rows each)
#define CB 6    // col-blocks per group (128 cols each)

typedef short s16x8 __attribute__((ext_vector_type(8)));
typedef float f32x4 __attribute__((ext_vector_type(4)));
typedef unsigned u32x4 __attribute__((ext_vector_type(4)));

__device__ __forceinline__ unsigned short f2b(float f) {
  unsigned u = __builtin_bit_cast(unsigned, f);
  u += 0x7FFFu + ((u >> 16) & 1u);
  return (unsigned short)(u >> 16);
}
__device__ __forceinline__ float b2f(unsigned short h) {
  unsigned u = ((unsigned)h) << 16;
  return __builtin_bit_cast(float, u);
}

// tanh(x) = 1 - 2/(1+e^{2x}); exact at +-inf, ~1e-7 rel err, no branches.
__device__ __forceinline__ float fast_tanh(float x) {
  float e = __builtin_amdgcn_exp2f(x * 2.8853900817779268f);  // e^{2x}
  return 1.0f - 2.0f * __builtin_amdgcn_rcpf(1.0f + e);
}

// One launch converts W_ih, W_fc, hidden fp32 -> bf16 (replaces 3 convs).
__global__ __launch_bounds__(256) void prep_kernel(
    const float* __restrict__ W_ih, const float* __restrict__ W_fc,
    const float* __restrict__ hidden, unsigned short* __restrict__ wih_b,
    unsigned short* __restrict__ wfc_b, unsigned short* __restrict__ h0) {
  int i = (blockIdx.x * 256 + threadIdx.x) * 4;
  const float* src;
  unsigned short* dst;
  int off;
  if (i < 589824) {
    src = W_ih; dst = wih_b; off = i;
  } else if (i < 1179648) {
    src = W_fc; dst = wfc_b; off = i - 589824;
  } else if (i < 1228800) {
    src = hidden; dst = h0; off = i - 1179648;
  } else {
    return;
  }
  float4 v = *(const float4*)(src + off);
  unsigned long long p = (unsigned long long)f2b(v.x)
      | ((unsigned long long)f2b(v.y) << 16)
      | ((unsigned long long)f2b(v.z) << 32)
      | ((unsigned long long)f2b(v.w) << 48);
  *(unsigned long long*)(dst + off) = p;
}

// C[r][n] = sum_k A[r][k] * W[n][k] + bias.  MODE0: A fp32 (x), bias1+bias2.
// MODE1: A bf16 (hseq, row-gathered: r=b*1024+s -> hseq[(s+1)*64+b]), bias1;
//        block (0,0) also writes the final-hidden floats (tail fold).
template <int MODE>
__global__ __launch_bounds__(256) void gemm_kernel(
    const void* __restrict__ Aptr, const unsigned short* __restrict__ Bw,
    float* __restrict__ C, const float* __restrict__ bias1,
    const float* __restrict__ bias2, const unsigned short* __restrict__ hfin,
    float* __restrict__ hfin_out) {
  __shared__ unsigned short As[128 * 64];
  __shared__ unsigned short Bs[128 * 64];
  const int tid = threadIdx.x;
  const int l = tid & 63;
  const int w = tid >> 6;
  const int wm = w >> 1, wn = w & 1;
  const int r0 = blockIdx.x * 128;
  const int n0 = blockIdx.y * 128;
  const int row16 = l & 15;
  const int g4 = l >> 4;
  const int swz = (l & 7) << 3;

  const int srow = tid >> 1;
  const int shalf = (tid & 1) * 32;
  size_t a_off;
  if (MODE == 0) {
    a_off = (size_t)(r0 + srow) * 768;
  } else {
    int ar = r0 + srow;
    a_off = ((size_t)((ar & 1023) + 1) * 64 + (ar >> 10)) * 768;
  }
  const size_t b_off = (size_t)(n0 + srow) * 768;
  const int swrow = (srow & 7) << 3;

  f32x4 acc[4][4] = {};

  for (int k0 = 0; k0 < 768; k0 += 64) {
    if (MODE == 0) {
      const float* Af = (const float*)Aptr + a_off + k0 + shalf;
#pragma unroll
      for (int jj = 0; jj < 4; ++jj) {
        float4 v0 = *(const float4*)(Af + jj * 8);
        float4 v1 = *(const float4*)(Af + jj * 8 + 4);
        uint4 p;
        p.x = f2b(v0.x) | ((unsigned)f2b(v0.y) << 16);
        p.y = f2b(v0.z) | ((unsigned)f2b(v0.w) << 16);
        p.z = f2b(v1.x) | ((unsigned)f2b(v1.y) << 16);
        p.w = f2b(v1.z) | ((unsigned)f2b(v1.w) << 16);
        int c = (shalf + jj * 8) ^ swrow;
        *(uint4*)(As + srow * 64 + c) = p;
      }
    } else {
      const unsigned short* Ab = (const unsigned short*)Aptr + a_off + k0 + shalf;
#pragma unroll
      for (int jj = 0; jj < 4; ++jj) {
        uint4 p = *(const uint4*)(Ab + jj * 8);
        int c = (shalf + jj * 8) ^ swrow;
        *(uint4*)(As + srow * 64 + c) = p;
      }
    }
    {
      const unsigned short* Bb = Bw + b_off + k0 + shalf;
#pragma unroll
      for (int jj = 0; jj < 4; ++jj) {
        uint4 p = *(const uint4*)(Bb + jj * 8);
        int c = (shalf + jj * 8) ^ swrow;
        *(uint4*)(Bs + srow * 64 + c) = p;
      }
    }
    __syncthreads();
#pragma unroll
    for (int kb = 0; kb < 2; ++kb) {
      int ccol = (kb * 32 + g4 * 8) ^ swz;
      s16x8 af[4], bfr[4];
#pragma unroll
      for (int mi = 0; mi < 4; ++mi)
        af[mi] = __builtin_bit_cast(
            s16x8, *(const uint4*)(As + (wm * 64 + mi * 16 + row16) * 64 + ccol));
#pragma unroll
      for (int ni = 0; ni < 4; ++ni)
        bfr[ni] = __builtin_bit_cast(
            s16x8, *(const uint4*)(Bs + (wn * 64 + ni * 16 + row16) * 64 + ccol));
#pragma unroll
      for (int mi = 0; mi < 4; ++mi)
#pragma unroll
        for (int ni = 0; ni < 4; ++ni)
          acc[mi][ni] = __builtin_amdgcn_mfma_f32_16x16x32_bf16(
              af[mi], bfr[ni], acc[mi][ni], 0, 0, 0);
    }
    __syncthreads();
  }
#pragma unroll
  for (int ni = 0; ni < 4; ++ni) {
    int col = n0 + wn * 64 + ni * 16 + row16;
    float bv = bias1[col] + (MODE == 0 ? bias2[col] : 0.0f);
#pragma unroll
    for (int mi = 0; mi < 4; ++mi) {
      int rbase = r0 + wm * 64 + mi * 16 + g4 * 4;
#pragma unroll
      for (int i = 0; i < 4; ++i)
        C[(size_t)(rbase + i) * 768 + col] = acc[mi][ni][i] + bv;
    }
  }
  // tail fold: final hidden bf16 -> f32 (one block only; 192 elems/thread)
  if (MODE == 1 && blockIdx.x == 0 && blockIdx.y == 0) {
    for (int i = tid; i < B_ * H_; i += 256) hfin_out[i] = b2f(hfin[i]);
  }
}

// Persistent recurrence (R18 = R14 exact): 48 blocks = 8 batch-groups
// (8 rows) x 6 col-blocks (128 cols), 512 threads.  Data-as-flag protocol
// (sc1/IF, zero-sentinel, memset-zeroed slab, self-staged own cols, paired
// 16B stores); 16-slot read swizzle with don't-care lanes.  Probed floor:
// ~2.06us/step = 1024 serial cross-XCD store->IF->poll RTs; compute ~6%.
__global__ __launch_bounds__(512) void scan_kernel(
    const float* __restrict__ W_hh, const float* __restrict__ xp,
    unsigned short* __restrict__ hseq) {
  __shared__ unsigned short hs[2][8 * 768];  // 2 x 12KB
  const int tid = threadIdx.x;
  const int l = tid & 63;
  const int w = tid >> 6;
  const int bg = blockIdx.x / CB;  // 0..7
  const int cb = blockIdx.x % CB;  // 0..5
  const int b0 = bg * 8;
  const int c0 = cb * 128;
  const int row16 = l & 15;
  const int row8 = row16 & 7;
  const int g4 = l >> 4;

  // pack W_hh fragments: A[row=l&15 (out col)][k = kb*32 + (l>>4)*8 + j]
  uint4 wfrag[24];
  {
    const float* wr = W_hh + (size_t)(c0 + w * 16 + row16) * 768;
#pragma unroll
    for (int kb = 0; kb < 24; ++kb) {
      int k0 = kb * 32 + g4 * 8;
      float4 v0 = *(const float4*)(wr + k0);
      float4 v1 = *(const float4*)(wr + k0 + 4);
      uint4 p;
      p.x = f2b(v0.x) | ((unsigned)f2b(v0.y) << 16);
      p.y = f2b(v0.z) | ((unsigned)f2b(v0.w) << 16);
      p.z = f2b(v1.x) | ((unsigned)f2b(v1.y) << 16);
      p.w = f2b(v1.z) | ((unsigned)f2b(v1.w) << 16);
      wfrag[kb] = p;
    }
  }

  // foreign-chunk geometry (t>=1): 80 foreign 16B chunks/row x 8 rows = 640
  const int c08 = cb * 16;
  const int nch = (tid < 128) ? 2 : 1;
  size_t gF[2];
  int lF[2];
#pragma unroll
  for (int j = 0; j < 2; ++j) {
    int fi = (j == 0) ? tid : (512 + (tid & 127));
    int row = fi / 80;
    int f = fi - row * 80;
    int col8 = f + (f >= c08 ? 16 : 0);
    gF[j] = (size_t)(b0 + row) * 768 + col8 * 8;
    lF[j] = row * 1536 + ((col8 * 16) ^ ((row & 7) << 4));
  }

  const size_t hcol = c0 + w * 16 + g4 * 4;
  unsigned short* hout_base = hseq + (size_t)(b0 + row8) * 768 + hcol;
  const float* xp_base = xp + (size_t)(b0 + row8) * 1024 * 768 + hcol;
  const int soff = row8 * 1536 + (((int)hcol * 2) ^ (row8 << 4));
  const int rswz = row16 << 4;  // 16-slot key; row16>=8 reads don't-care data
  const bool owner = (row16 < 8);

  for (int t = 0; t < S_; ++t) {
    char* lb = (char*)hs[t & 1];
    float4 xpv = *(const float4*)(xp_base + (size_t)t * 768);  // off crit path
    const unsigned short* hin = hseq + (size_t)t * (B_ * H_);
    if (t == 0) {
      // h0 pre-written by prep kernel; full slab = 768 chunks.
      uint4 cv0[2];
      int nj = (tid < 256) ? 2 : 1;
#pragma unroll
      for (int j = 0; j < 2; ++j) {
        if (j < nj) {
          int ch = (j == 0) ? tid : (512 + (tid & 255));
          int row = ch / 96;
          int col8 = ch - row * 96;
          asm volatile("global_load_dwordx4 %0, %1, off sc1"
                       : "=&v"(cv0[j])
                       : "v"(hin + (size_t)(b0 + row) * 768 + col8 * 8));
        }
      }
      asm volatile("s_waitcnt vmcnt(0)" ::: "memory");
      __builtin_amdgcn_sched_barrier(0);
#pragma unroll
      for (int j = 0; j < 2; ++j) {
        if (j < nj) {
          int ch = (j == 0) ? tid : (512 + (tid & 255));
          int row = ch / 96;
          int col8 = ch - row * 96;
          *(uint4*)(lb + row * 1536 + ((col8 * 16) ^ ((row & 7) << 4))) =
              cv0[j];
        }
      }
    } else {
      uint4 cv[2];
      unsigned done = 0;
      const unsigned full = (nch == 2) ? 3u : 1u;
      while (done != full) {
        if (!(done & 1))
          asm volatile("global_load_dwordx4 %0, %1, off sc1"
                       : "=&v"(cv[0]) : "v"(hin + gF[0]));
        if (nch == 2 && !(done & 2))
          asm volatile("global_load_dwordx4 %0, %1, off sc1"
                       : "=&v"(cv[1]) : "v"(hin + gF[1]));
        asm volatile("s_waitcnt vmcnt(0)" ::: "memory");
        __builtin_amdgcn_sched_barrier(0);  // keep checks after the waitcnt
        if (!(done & 1) && (cv[0].x | cv[0].y) != 0 && (cv[0].z | cv[0].w) != 0) {
          done |= 1;
          *(uint4*)(lb + lF[0]) = cv[0];
        }
        if (nch == 2 && !(done & 2) && (cv[1].x | cv[1].y) != 0 &&
            (cv[1].z | cv[1].w) != 0) {
          done |= 2;
          *(uint4*)(lb + lF[1]) = cv[1];
        }
      }
    }
    __syncthreads();

    uint4 hb[24];
    const char* rb = lb + row8 * 1536;
#pragma unroll
    for (int kb = 0; kb < 24; ++kb)
      hb[kb] = *(const uint4*)(rb + ((kb * 64 + g4 * 16) ^ rswz));

    f32x4 acc0 = {xpv.x, xpv.y, xpv.z, xpv.w};
    f32x4 acc1 = {0.f, 0.f, 0.f, 0.f};
    f32x4 acc2 = {0.f, 0.f, 0.f, 0.f};
    f32x4 acc3 = {0.f, 0.f, 0.f, 0.f};
#pragma unroll
    for (int kb = 0; kb < 24; kb += 4) {
      acc0 = __builtin_amdgcn_mfma_f32_16x16x32_bf16(
          __builtin_bit_cast(s16x8, wfrag[kb]),
          __builtin_bit_cast(s16x8, hb[kb]), acc0, 0, 0, 0);
      acc1 = __builtin_amdgcn_mfma_f32_16x16x32_bf16(
          __builtin_bit_cast(s16x8, wfrag[kb + 1]),
          __builtin_bit_cast(s16x8, hb[kb + 1]), acc1, 0, 0, 0);
      acc2 = __builtin_amdgcn_mfma_f32_16x16x32_bf16(
          __builtin_bit_cast(s16x8, wfrag[kb + 2]),
          __builtin_bit_cast(s16x8, hb[kb + 2]), acc2, 0, 0, 0);
      acc3 = __builtin_amdgcn_mfma_f32_16x16x32_bf16(
          __builtin_bit_cast(s16x8, wfrag[kb + 3]),
          __builtin_bit_cast(s16x8, hb[kb + 3]), acc3, 0, 0, 0);
    }
    f32x4 g = (acc0 + acc1) + (acc2 + acc3);
    float t0 = fast_tanh(g[0]), t1 = fast_tanh(g[1]);
    float t2 = fast_tanh(g[2]), t3 = fast_tanh(g[3]);
    unsigned long long pk = (unsigned long long)f2b(t0)
        | ((unsigned long long)f2b(t1) << 16)
        | ((unsigned long long)f2b(t2) << 32)
        | ((unsigned long long)f2b(t3) << 48);
    if (pk == 0) pk = 1;  // readiness sentinel: never store an all-zero word

    // self-stage own cols for step t+1 (single writer; rows 0..7 only)
    if (owner) *(unsigned long long*)((char*)hs[(t + 1) & 1] + soff) = pk;

    // paired 16B global store: lanes (l, l^16) -> even-g4 owner lane stores
    unsigned long long po = __shfl(pk, l ^ 16);
    if (owner && (g4 & 1) == 0) {
      u32x4 st;
      st[0] = (unsigned)pk;
      st[1] = (unsigned)(pk >> 32);
      st[2] = (unsigned)po;
      st[3] = (unsigned)(po >> 32);
      asm volatile("global_store_dwordx4 %0, %1, off sc1" ::"v"(
                       hout_base + (size_t)(t + 1) * (B_ * H_)),
                   "v"(st)
                   : "memory");
    }
    // no trailing barrier: double-buffered LDS; lap-safety via the
    // cross-block store->poll dependency chain (see R13 note).
  }
}

extern "C" void kernel_launch(void* const* d_in, const int* in_sizes, int n_in,
                              void* d_out, int out_size, void* d_ws,
                              size_t ws_size, hipStream_t stream) {
  const float* hidden = (const float*)d_in[0];
  const float* x = (const float*)d_in[1];
  const float* W_ih = (const float*)d_in[2];
  const float* W_hh = (const float*)d_in[3];
  const float* b_ih = (const float*)d_in[4];
  const float* b_hh = (const float*)d_in[5];
  const float* W_fc = (const float*)d_in[6];
  const float* b_fc = (const float*)d_in[7];
  float* out = (float*)d_out;
  float* xp = out;  // xp [B*S][768] fp32 reuses the logits region

  char* ws = (char*)d_ws;
  unsigned short* hseq = (unsigned short*)ws;  // [(S+1)][B][H] bf16
  size_t hseq_elems = (size_t)(S_ + 1) * B_ * H_;
  unsigned short* wih_b = hseq + hseq_elems;
  unsigned short* wfc_b = wih_b + 768 * 768;

  // zero h[1..S]: required every launch (data-as-flag poll; ws is not
  // re-poisoned between replays)
  (void)hipMemsetAsync(hseq + (size_t)B_ * H_, 0, (size_t)S_ * B_ * H_ * 2,
                       stream);
  prep_kernel<<<1200, 256, 0, stream>>>(W_ih, W_fc, hidden, wih_b, wfc_b,
                                        hseq);
  dim3 grid(512, 6);
  gemm_kernel<0><<<grid, 256, 0, stream>>>(x, wih_b, xp, b_ih, b_hh, nullptr,
                                           nullptr);
  scan_kernel<<<GB * CB, 512, 0, stream>>>(W_hh, xp, hseq);
  gemm_kernel<1><<<grid, 256, 0, stream>>>(hseq, wfc_b, out, b_fc, nullptr,
                                           hseq + (size_t)S_ * B_ * H_,
                                           out + (size_t)65536 * 768);
}

// Round 19
// 2394.671 us; speedup vs baseline: 3.2855x; 1.0737x over previous
//
#include <hip/hip_runtime.h>

#define B_ 64
#define S_ 1024
#define H_ 768
#define GB 8    // batch groups (8 rows each)
#define CB 6    // col-blocks per group (128 cols each)
#define NWRK 208
#define NST 1536  // gemm1 supertiles: 512 r-tiles x 3 n-supertiles

typedef short s16x8 __attribute__((ext_vector_type(8)));
typedef float f32x4 __attribute__((ext_vector_type(4)));
typedef unsigned u32x4 __attribute__((ext_vector_type(4)));

__device__ __forceinline__ unsigned short f2b(float f) {
  unsigned u = __builtin_bit_cast(unsigned, f);
  u += 0x7FFFu + ((u >> 16) & 1u);
  return (unsigned short)(u >> 16);
}
__device__ __forceinline__ float b2f(unsigned short h) {
  unsigned u = ((unsigned)h) << 16;
  return __builtin_bit_cast(float, u);
}

// tanh(x) = 1 - 2/(1+e^{2x}); exact at +-inf, ~1e-7 rel err, no branches.
__device__ __forceinline__ float fast_tanh(float x) {
  float e = __builtin_amdgcn_exp2f(x * 2.8853900817779268f);  // e^{2x}
  return 1.0f - 2.0f * __builtin_amdgcn_rcpf(1.0f + e);
}

// One launch converts W_ih, W_fc, hidden fp32 -> bf16.
__global__ __launch_bounds__(256) void prep_kernel(
    const float* __restrict__ W_ih, const float* __restrict__ W_fc,
    const float* __restrict__ hidden, unsigned short* __restrict__ wih_b,
    unsigned short* __restrict__ wfc_b, unsigned short* __restrict__ h0) {
  int i = (blockIdx.x * 256 + threadIdx.x) * 4;
  const float* src;
  unsigned short* dst;
  int off;
  if (i < 589824) {
    src = W_ih; dst = wih_b; off = i;
  } else if (i < 1179648) {
    src = W_fc; dst = wfc_b; off = i - 589824;
  } else if (i < 1228800) {
    src = hidden; dst = h0; off = i - 1179648;
  } else {
    return;
  }
  float4 v = *(const float4*)(src + off);
  unsigned long long p = (unsigned long long)f2b(v.x)
      | ((unsigned long long)f2b(v.y) << 16)
      | ((unsigned long long)f2b(v.z) << 32)
      | ((unsigned long long)f2b(v.w) << 48);
  *(unsigned long long*)(dst + off) = p;
}

// xp GEMM (serial, unchanged): C[r][n] = x[r]. W_ih[n] + b_ih[n] + b_hh[n].
__global__ __launch_bounds__(256) void gemm0_kernel(
    const float* __restrict__ Aptr, const unsigned short* __restrict__ Bw,
    float* __restrict__ C, const float* __restrict__ bias1,
    const float* __restrict__ bias2) {
  __shared__ unsigned short As[128 * 64];
  __shared__ unsigned short Bs[128 * 64];
  const int tid = threadIdx.x;
  const int l = tid & 63;
  const int w = tid >> 6;
  const int wm = w >> 1, wn = w & 1;
  const int r0 = blockIdx.x * 128;
  const int n0 = blockIdx.y * 128;
  const int row16 = l & 15;
  const int g4 = l >> 4;
  const int swz = (l & 7) << 3;

  const int srow = tid >> 1;
  const int shalf = (tid & 1) * 32;
  size_t a_off = (size_t)(r0 + srow) * 768;
  const size_t b_off = (size_t)(n0 + srow) * 768;
  const int swrow = (srow & 7) << 3;

  f32x4 acc[4][4] = {};

  for (int k0 = 0; k0 < 768; k0 += 64) {
    {
      const float* Af = Aptr + a_off + k0 + shalf;
#pragma unroll
      for (int jj = 0; jj < 4; ++jj) {
        float4 v0 = *(const float4*)(Af + jj * 8);
        float4 v1 = *(const float4*)(Af + jj * 8 + 4);
        uint4 p;
        p.x = f2b(v0.x) | ((unsigned)f2b(v0.y) << 16);
        p.y = f2b(v0.z) | ((unsigned)f2b(v0.w) << 16);
        p.z = f2b(v1.x) | ((unsigned)f2b(v1.y) << 16);
        p.w = f2b(v1.z) | ((unsigned)f2b(v1.w) << 16);
        int c = (shalf + jj * 8) ^ swrow;
        *(uint4*)(As + srow * 64 + c) = p;
      }
    }
    {
      const unsigned short* Bb = Bw + b_off + k0 + shalf;
#pragma unroll
      for (int jj = 0; jj < 4; ++jj) {
        uint4 p = *(const uint4*)(Bb + jj * 8);
        int c = (shalf + jj * 8) ^ swrow;
        *(uint4*)(Bs + srow * 64 + c) = p;
      }
    }
    __syncthreads();
#pragma unroll
    for (int kb = 0; kb < 2; ++kb) {
      int ccol = (kb * 32 + g4 * 8) ^ swz;
      s16x8 af[4], bfr[4];
#pragma unroll
      for (int mi = 0; mi < 4; ++mi)
        af[mi] = __builtin_bit_cast(
            s16x8, *(const uint4*)(As + (wm * 64 + mi * 16 + row16) * 64 + ccol));
#pragma unroll
      for (int ni = 0; ni < 4; ++ni)
        bfr[ni] = __builtin_bit_cast(
            s16x8, *(const uint4*)(Bs + (wn * 64 + ni * 16 + row16) * 64 + ccol));
#pragma unroll
      for (int mi = 0; mi < 4; ++mi)
#pragma unroll
        for (int ni = 0; ni < 4; ++ni)
          acc[mi][ni] = __builtin_amdgcn_mfma_f32_16x16x32_bf16(
              af[mi], bfr[ni], acc[mi][ni], 0, 0, 0);
    }
    __syncthreads();
  }
#pragma unroll
  for (int ni = 0; ni < 4; ++ni) {
    int col = n0 + wn * 64 + ni * 16 + row16;
    float bv = bias1[col] + bias2[col];
#pragma unroll
    for (int mi = 0; mi < 4; ++mi) {
      int rbase = r0 + wm * 64 + mi * 16 + g4 * 4;
#pragma unroll
      for (int i = 0; i < 4; ++i)
        C[(size_t)(rbase + i) * 768 + col] = acc[mi][ni][i] + bv;
    }
  }
}

// gate: wait until h[trow][b] is fully written (6 chunks, one per col-block;
// col-blocks write sequentially in t so nonzero => all rows <= trow done).
__device__ __forceinline__ void wait_rows(const unsigned short* __restrict__ hseq,
                                          int trow, int b) {
  const int li = threadIdx.x & 63;
  const unsigned short* p =
      hseq + ((size_t)trow * 64 + b) * 768 + (li < 6 ? li * 128 : 0);
  while (true) {
    uint4 v;
    asm volatile("global_load_dwordx4 %0, %1, off sc1" : "=&v"(v) : "v"(p));
    asm volatile("s_waitcnt vmcnt(0)" ::: "memory");
    __builtin_amdgcn_sched_barrier(0);
    bool ok = (li >= 6) || ((v.x | v.y) != 0 && (v.z | v.w) != 0);
    if (__all(ok)) return;
    __builtin_amdgcn_s_sleep(8);
  }
}

// Fused scan + gemm1 (R19): 256 blocks x 512 thr = 1 block/CU, ALL resident
// by construction (no dispatch-order dependence; workers poll scan output,
// scan never waits on workers -> deadlock-free).  Blocks 0-47: R14 scan
// verbatim.  Blocks 48-255: 208 workers x ~7.4 supertiles (128r x 256n),
// band-major; per-tile gate = wait_rows, A staged with sc1 (no reuse).
__global__ __launch_bounds__(512) void fused_kernel(
    const float* __restrict__ W_hh, const float* __restrict__ xp,
    unsigned short* __restrict__ hseq, const unsigned short* __restrict__ wfc,
    const float* __restrict__ b_fc, float* __restrict__ out,
    float* __restrict__ hfin_out) {
  __shared__ char smem[49152];
  const int tid = threadIdx.x;
  const int l = tid & 63;
  const int w = tid >> 6;
  const int row16 = l & 15;
  const int g4 = l >> 4;

  if (blockIdx.x < 48) {
    // ---------------- scan (R14 exact) ----------------
    unsigned short* hs0 = (unsigned short*)smem;
    unsigned short* hs1 = hs0 + 8 * 768;
    const int bg = blockIdx.x / CB;
    const int cb = blockIdx.x % CB;
    const int b0 = bg * 8;
    const int c0 = cb * 128;
    const int row8 = row16 & 7;

    uint4 wfrag[24];
    {
      const float* wr = W_hh + (size_t)(c0 + w * 16 + row16) * 768;
#pragma unroll
      for (int kb = 0; kb < 24; ++kb) {
        int k0 = kb * 32 + g4 * 8;
        float4 v0 = *(const float4*)(wr + k0);
        float4 v1 = *(const float4*)(wr + k0 + 4);
        uint4 p;
        p.x = f2b(v0.x) | ((unsigned)f2b(v0.y) << 16);
        p.y = f2b(v0.z) | ((unsigned)f2b(v0.w) << 16);
        p.z = f2b(v1.x) | ((unsigned)f2b(v1.y) << 16);
        p.w = f2b(v1.z) | ((unsigned)f2b(v1.w) << 16);
        wfrag[kb] = p;
      }
    }

    const int c08 = cb * 16;
    const int nch = (tid < 128) ? 2 : 1;
    size_t gF[2];
    int lF[2];
#pragma unroll
    for (int j = 0; j < 2; ++j) {
      int fi = (j == 0) ? tid : (512 + (tid & 127));
      int row = fi / 80;
      int f = fi - row * 80;
      int col8 = f + (f >= c08 ? 16 : 0);
      gF[j] = (size_t)(b0 + row) * 768 + col8 * 8;
      lF[j] = row * 1536 + ((col8 * 16) ^ ((row & 7) << 4));
    }

    const size_t hcol = c0 + w * 16 + g4 * 4;
    unsigned short* hout_base = hseq + (size_t)(b0 + row8) * 768 + hcol;
    const float* xp_base = xp + (size_t)(b0 + row8) * 1024 * 768 + hcol;
    const int soff = row8 * 1536 + (((int)hcol * 2) ^ (row8 << 4));
    const int rswz = row16 << 4;
    const bool owner = (row16 < 8);

    for (int t = 0; t < S_; ++t) {
      char* lb = (char*)((t & 1) ? hs1 : hs0);
      float4 xpv = *(const float4*)(xp_base + (size_t)t * 768);
      const unsigned short* hin = hseq + (size_t)t * (B_ * H_);
      if (t == 0) {
        uint4 cv0[2];
        int nj = (tid < 256) ? 2 : 1;
#pragma unroll
        for (int j = 0; j < 2; ++j) {
          if (j < nj) {
            int ch = (j == 0) ? tid : (512 + (tid & 255));
            int row = ch / 96;
            int col8 = ch - row * 96;
            asm volatile("global_load_dwordx4 %0, %1, off sc1"
                         : "=&v"(cv0[j])
                         : "v"(hin + (size_t)(b0 + row) * 768 + col8 * 8));
          }
        }
        asm volatile("s_waitcnt vmcnt(0)" ::: "memory");
        __builtin_amdgcn_sched_barrier(0);
#pragma unroll
        for (int j = 0; j < 2; ++j) {
          if (j < nj) {
            int ch = (j == 0) ? tid : (512 + (tid & 255));
            int row = ch / 96;
            int col8 = ch - row * 96;
            *(uint4*)(lb + row * 1536 + ((col8 * 16) ^ ((row & 7) << 4))) =
                cv0[j];
          }
        }
      } else {
        uint4 cv[2];
        unsigned done = 0;
        const unsigned full = (nch == 2) ? 3u : 1u;
        while (done != full) {
          if (!(done & 1))
            asm volatile("global_load_dwordx4 %0, %1, off sc1"
                         : "=&v"(cv[0]) : "v"(hin + gF[0]));
          if (nch == 2 && !(done & 2))
            asm volatile("global_load_dwordx4 %0, %1, off sc1"
                         : "=&v"(cv[1]) : "v"(hin + gF[1]));
          asm volatile("s_waitcnt vmcnt(0)" ::: "memory");
          __builtin_amdgcn_sched_barrier(0);
          if (!(done & 1) && (cv[0].x | cv[0].y) != 0 &&
              (cv[0].z | cv[0].w) != 0) {
            done |= 1;
            *(uint4*)(lb + lF[0]) = cv[0];
          }
          if (nch == 2 && !(done & 2) && (cv[1].x | cv[1].y) != 0 &&
              (cv[1].z | cv[1].w) != 0) {
            done |= 2;
            *(uint4*)(lb + lF[1]) = cv[1];
          }
        }
      }
      __syncthreads();

      uint4 hb[24];
      const char* rb = lb + row8 * 1536;
#pragma unroll
      for (int kb = 0; kb < 24; ++kb)
        hb[kb] = *(const uint4*)(rb + ((kb * 64 + g4 * 16) ^ rswz));

      f32x4 acc0 = {xpv.x, xpv.y, xpv.z, xpv.w};
      f32x4 acc1 = {0.f, 0.f, 0.f, 0.f};
      f32x4 acc2 = {0.f, 0.f, 0.f, 0.f};
      f32x4 acc3 = {0.f, 0.f, 0.f, 0.f};
#pragma unroll
      for (int kb = 0; kb < 24; kb += 4) {
        acc0 = __builtin_amdgcn_mfma_f32_16x16x32_bf16(
            __builtin_bit_cast(s16x8, wfrag[kb]),
            __builtin_bit_cast(s16x8, hb[kb]), acc0, 0, 0, 0);
        acc1 = __builtin_amdgcn_mfma_f32_16x16x32_bf16(
            __builtin_bit_cast(s16x8, wfrag[kb + 1]),
            __builtin_bit_cast(s16x8, hb[kb + 1]), acc1, 0, 0, 0);
        acc2 = __builtin_amdgcn_mfma_f32_16x16x32_bf16(
            __builtin_bit_cast(s16x8, wfrag[kb + 2]),
            __builtin_bit_cast(s16x8, hb[kb + 2]), acc2, 0, 0, 0);
        acc3 = __builtin_amdgcn_mfma_f32_16x16x32_bf16(
            __builtin_bit_cast(s16x8, wfrag[kb + 3]),
            __builtin_bit_cast(s16x8, hb[kb + 3]), acc3, 0, 0, 0);
      }
      f32x4 g = (acc0 + acc1) + (acc2 + acc3);
      float t0 = fast_tanh(g[0]), t1 = fast_tanh(g[1]);
      float t2 = fast_tanh(g[2]), t3 = fast_tanh(g[3]);
      unsigned long long pk = (unsigned long long)f2b(t0)
          | ((unsigned long long)f2b(t1) << 16)
          | ((unsigned long long)f2b(t2) << 32)
          | ((unsigned long long)f2b(t3) << 48);
      if (pk == 0) pk = 1;

      if (owner)
        *(unsigned long long*)((char*)((t & 1) ? hs0 : hs1) + soff) = pk;

      unsigned long long po = __shfl(pk, l ^ 16);
      if (owner && (g4 & 1) == 0) {
        u32x4 st;
        st[0] = (unsigned)pk;
        st[1] = (unsigned)(pk >> 32);
        st[2] = (unsigned)po;
        st[3] = (unsigned)(po >> 32);
        asm volatile("global_store_dwordx4 %0, %1, off sc1" ::"v"(
                         hout_base + (size_t)(t + 1) * (B_ * H_)),
                     "v"(st)
                     : "memory");
      }
    }
  } else {
    // ---------------- gemm1 workers ----------------
    unsigned short* As = (unsigned short*)smem;          // 128 x 64
    unsigned short* Bs = As + 128 * 64;                  // 256 x 64
    const int wb = blockIdx.x - 48;
    const int wm = w >> 2, wn = w & 3;
    const int swz = (l & 7) << 3;

    for (int q = wb; q < NST; q += NWRK) {
      int band = q / 192;
      int rem = q - band * 192;
      int b = rem / 3;
      int ns = rem - b * 3;
      int s0 = band * 128;
      int r0 = b * 1024 + s0;
      int n0 = ns * 256;

      wait_rows(hseq, s0 + 128, b);

      f32x4 acc[4][4] = {};
      for (int k0 = 0; k0 < 768; k0 += 64) {
        if (tid < 256) {  // A-stage: 128 rows, row-gathered, sc1
          int srow = tid >> 1;
          int shalf = (tid & 1) * 32;
          int ar = r0 + srow;
          const unsigned short* Ab =
              hseq + ((size_t)((ar & 1023) + 1) * 64 + (ar >> 10)) * 768 + k0 +
              shalf;
          uint4 pa[4];
#pragma unroll
          for (int jj = 0; jj < 4; ++jj)
            asm volatile("global_load_dwordx4 %0, %1, off sc1"
                         : "=&v"(pa[jj]) : "v"(Ab + jj * 8));
          asm volatile("s_waitcnt vmcnt(0)" ::: "memory");
          __builtin_amdgcn_sched_barrier(0);
          int swrow = (srow & 7) << 3;
#pragma unroll
          for (int jj = 0; jj < 4; ++jj) {
            int c = (shalf + jj * 8) ^ swrow;
            *(uint4*)(As + srow * 64 + c) = pa[jj];
          }
        } else {  // B-stage: 256 rows, 1 thread/row, plain cached loads
          int u = tid & 255;
          const unsigned short* Bb = wfc + (size_t)(n0 + u) * 768 + k0;
          int swrow = (u & 7) << 3;
#pragma unroll
          for (int jj = 0; jj < 2; ++jj) {
            uint4 p = *(const uint4*)(Bb + jj * 32 + ((jj == 0) ? 0 : 0));
            // two 32-elem halves: shalf = jj*32, chunks at +0,+8,+16,+24
          }
          // stage both halves, 4 chunks of 8 elems each per half
#pragma unroll
          for (int hh = 0; hh < 2; ++hh) {
            int shalf = hh * 32;
#pragma unroll
            for (int jj = 0; jj < 4; ++jj) {
              uint4 p = *(const uint4*)(Bb + shalf + jj * 8);
              int c = (shalf + jj * 8) ^ swrow;
              *(uint4*)(Bs + u * 64 + c) = p;
            }
          }
        }
        __syncthreads();
#pragma unroll
        for (int kb = 0; kb < 2; ++kb) {
          int ccol = (kb * 32 + g4 * 8) ^ swz;
          s16x8 af[4], bfr[4];
#pragma unroll
          for (int mi = 0; mi < 4; ++mi)
            af[mi] = __builtin_bit_cast(
                s16x8,
                *(const uint4*)(As + (wm * 64 + mi * 16 + row16) * 64 + ccol));
#pragma unroll
          for (int ni = 0; ni < 4; ++ni)
            bfr[ni] = __builtin_bit_cast(
                s16x8,
                *(const uint4*)(Bs + (wn * 64 + ni * 16 + row16) * 64 + ccol));
#pragma unroll
          for (int mi = 0; mi < 4; ++mi)
#pragma unroll
            for (int ni = 0; ni < 4; ++ni)
              acc[mi][ni] = __builtin_amdgcn_mfma_f32_16x16x32_bf16(
                  af[mi], bfr[ni], acc[mi][ni], 0, 0, 0);
        }
        __syncthreads();
      }
#pragma unroll
      for (int ni = 0; ni < 4; ++ni) {
        int col = n0 + wn * 64 + ni * 16 + row16;
        float bv = b_fc[col];
#pragma unroll
        for (int mi = 0; mi < 4; ++mi) {
          int rbase = r0 + wm * 64 + mi * 16 + g4 * 4;
#pragma unroll
          for (int i = 0; i < 4; ++i)
            out[(size_t)(rbase + i) * 768 + col] = acc[mi][ni][i] + bv;
        }
      }
    }
    // tail fold (worker 0): final hidden bf16 -> f32 after h[1024] complete
    if (wb == 0) {
      for (int g = 0; g < GB; ++g) wait_rows(hseq, 1024, g * 8);
      const unsigned short* hfin = hseq + (size_t)S_ * B_ * H_;
      for (int i = tid; i < (B_ * H_) / 8; i += 512) {
        uint4 v = *(const uint4*)(hfin + i * 8);
        float4 o0, o1;
        o0.x = b2f((unsigned short)(v.x & 0xFFFF));
        o0.y = b2f((unsigned short)(v.x >> 16));
        o0.z = b2f((unsigned short)(v.y & 0xFFFF));
        o0.w = b2f((unsigned short)(v.y >> 16));
        o1.x = b2f((unsigned short)(v.z & 0xFFFF));
        o1.y = b2f((unsigned short)(v.z >> 16));
        o1.z = b2f((unsigned short)(v.w & 0xFFFF));
        o1.w = b2f((unsigned short)(v.w >> 16));
        *(float4*)(hfin_out + i * 8) = o0;
        *(float4*)(hfin_out + i * 8 + 4) = o1;
      }
    }
  }
}

extern "C" void kernel_launch(void* const* d_in, const int* in_sizes, int n_in,
                              void* d_out, int out_size, void* d_ws,
                              size_t ws_size, hipStream_t stream) {
  const float* hidden = (const float*)d_in[0];
  const float* x = (const float*)d_in[1];
  const float* W_ih = (const float*)d_in[2];
  const float* W_hh = (const float*)d_in[3];
  const float* b_ih = (const float*)d_in[4];
  const float* b_hh = (const float*)d_in[5];
  const float* W_fc = (const float*)d_in[6];
  const float* b_fc = (const float*)d_in[7];
  float* out = (float*)d_out;
  float* xp = out;  // xp [B*S][768] fp32; logits overwrite it tile-by-tile
                    // (tile (b,s-band) writes only after h[s0+128] exists,
                    // which requires xp rows [s0,s0+128) already consumed)

  char* ws = (char*)d_ws;
  unsigned short* hseq = (unsigned short*)ws;  // [(S+1)][B][H] bf16
  size_t hseq_elems = (size_t)(S_ + 1) * B_ * H_;
  unsigned short* wih_b = hseq + hseq_elems;
  unsigned short* wfc_b = wih_b + 768 * 768;

  // zero h[1..S]: required every launch (data-as-flag poll; ws is not
  // re-poisoned between replays)
  (void)hipMemsetAsync(hseq + (size_t)B_ * H_, 0, (size_t)S_ * B_ * H_ * 2,
                       stream);
  prep_kernel<<<1200, 256, 0, stream>>>(W_ih, W_fc, hidden, wih_b, wfc_b,
                                        hseq);
  dim3 grid(512, 6);
  gemm0_kernel<<<grid, 256, 0, stream>>>(x, wih_b, xp, b_ih, b_hh);
  fused_kernel<<<256, 512, 0, stream>>>(W_hh, xp, hseq, wfc_b, b_fc, out,
                                        out + (size_t)65536 * 768);
}

// Round 20
// 2237.133 us; speedup vs baseline: 3.5169x; 1.0704x over previous
//
#include <hip/hip_runtime.h>

#define B_ 64
#define S_ 1024
#define H_ 768
#define GB 8    // batch groups (8 rows each)
#define CB 6    // col-blocks per group (128 cols each)
#define NWRK 208
#define NTILE 3072  // 2 x 1536 supertiles (gemm0 + gemm1), 128r x 256n each

typedef short s16x8 __attribute__((ext_vector_type(8)));
typedef float f32x4 __attribute__((ext_vector_type(4)));
typedef unsigned u32x4 __attribute__((ext_vector_type(4)));

__device__ __forceinline__ unsigned short f2b(float f) {
  unsigned u = __builtin_bit_cast(unsigned, f);
  u += 0x7FFFu + ((u >> 16) & 1u);
  return (unsigned short)(u >> 16);
}
__device__ __forceinline__ float b2f(unsigned short h) {
  unsigned u = ((unsigned)h) << 16;
  return __builtin_bit_cast(float, u);
}

// tanh(x) = 1 - 2/(1+e^{2x}); exact at +-inf, ~1e-7 rel err, no branches.
__device__ __forceinline__ float fast_tanh(float x) {
  float e = __builtin_amdgcn_exp2f(x * 2.8853900817779268f);  // e^{2x}
  return 1.0f - 2.0f * __builtin_amdgcn_rcpf(1.0f + e);
}

// One launch converts W_ih, W_fc, hidden fp32 -> bf16.
__global__ __launch_bounds__(256) void prep_kernel(
    const float* __restrict__ W_ih, const float* __restrict__ W_fc,
    const float* __restrict__ hidden, unsigned short* __restrict__ wih_b,
    unsigned short* __restrict__ wfc_b, unsigned short* __restrict__ h0) {
  int i = (blockIdx.x * 256 + threadIdx.x) * 4;
  const float* src;
  unsigned short* dst;
  int off;
  if (i < 589824) {
    src = W_ih; dst = wih_b; off = i;
  } else if (i < 1179648) {
    src = W_fc; dst = wfc_b; off = i - 589824;
  } else if (i < 1228800) {
    src = hidden; dst = h0; off = i - 1179648;
  } else {
    return;
  }
  float4 v = *(const float4*)(src + off);
  unsigned long long p = (unsigned long long)f2b(v.x)
      | ((unsigned long long)f2b(v.y) << 16)
      | ((unsigned long long)f2b(v.z) << 32)
      | ((unsigned long long)f2b(v.w) << 48);
  *(unsigned long long*)(dst + off) = p;
}

// gate: wait until h[trow][b] is fully written (6 chunks, one per col-block).
__device__ __forceinline__ void wait_rows(const unsigned short* __restrict__ hseq,
                                          int trow, int b) {
  const int li = threadIdx.x & 63;
  const unsigned short* p =
      hseq + ((size_t)trow * 64 + b) * 768 + (li < 6 ? li * 128 : 0);
  while (true) {
    uint4 v;
    asm volatile("global_load_dwordx4 %0, %1, off sc1" : "=&v"(v) : "v"(p));
    asm volatile("s_waitcnt vmcnt(0)" ::: "memory");
    __builtin_amdgcn_sched_barrier(0);
    bool ok = (li >= 6) || ((v.x | v.y) != 0 && (v.z | v.w) != 0);
    if (__all(ok)) return;
    __builtin_amdgcn_s_sleep(8);
  }
}

// Fused scan + gemm0 + gemm1 (R20): 256 blocks x 512 thr = 1 block/CU, all
// resident by construction.  Blocks 0-47: R14 scan + overlapped xp poll.
// Blocks 48-255: 208 workers over a band-interleaved queue of 3072 tiles:
// slots g0b0,g0b1,{g1b(p),g0b(p+2)}p=0..5,g1b6,g1b7 — xp production stays
// >=2 bands ahead of the scan; g1 tiles gate on h (wait_rows).  Deadlock-
// free by slot induction: a worker waiting at slot s implies all g0 slots
// <s are done => scan progresses => the gate opens.  xp crosses XCDs: sc1
// stores with never-zero sentinel; scan issues its xp load sc1 before the
// h-poll (latency hidden) and verifies after (sched_barrier pins the check).
__global__ __launch_bounds__(512) void fused_kernel(
    const float* __restrict__ W_hh, const float* __restrict__ x,
    const unsigned short* __restrict__ wih, float* __restrict__ xp,
    unsigned short* __restrict__ hseq, const unsigned short* __restrict__ wfc,
    const float* __restrict__ b_ih, const float* __restrict__ b_hh,
    const float* __restrict__ b_fc, float* __restrict__ out,
    float* __restrict__ hfin_out) {
  __shared__ char smem[49152];
  const int tid = threadIdx.x;
  const int l = tid & 63;
  const int w = tid >> 6;
  const int row16 = l & 15;
  const int g4 = l >> 4;

  if (blockIdx.x < 48) {
    // ---------------- scan (R14 core + xp poll) ----------------
    unsigned short* hs0 = (unsigned short*)smem;
    unsigned short* hs1 = hs0 + 8 * 768;
    const int bg = blockIdx.x / CB;
    const int cb = blockIdx.x % CB;
    const int b0 = bg * 8;
    const int c0 = cb * 128;
    const int row8 = row16 & 7;

    uint4 wfrag[24];
    {
      const float* wr = W_hh + (size_t)(c0 + w * 16 + row16) * 768;
#pragma unroll
      for (int kb = 0; kb < 24; ++kb) {
        int k0 = kb * 32 + g4 * 8;
        float4 v0 = *(const float4*)(wr + k0);
        float4 v1 = *(const float4*)(wr + k0 + 4);
        uint4 p;
        p.x = f2b(v0.x) | ((unsigned)f2b(v0.y) << 16);
        p.y = f2b(v0.z) | ((unsigned)f2b(v0.w) << 16);
        p.z = f2b(v1.x) | ((unsigned)f2b(v1.y) << 16);
        p.w = f2b(v1.z) | ((unsigned)f2b(v1.w) << 16);
        wfrag[kb] = p;
      }
    }

    const int c08 = cb * 16;
    const int nch = (tid < 128) ? 2 : 1;
    size_t gF[2];
    int lF[2];
#pragma unroll
    for (int j = 0; j < 2; ++j) {
      int fi = (j == 0) ? tid : (512 + (tid & 127));
      int row = fi / 80;
      int f = fi - row * 80;
      int col8 = f + (f >= c08 ? 16 : 0);
      gF[j] = (size_t)(b0 + row) * 768 + col8 * 8;
      lF[j] = row * 1536 + ((col8 * 16) ^ ((row & 7) << 4));
    }

    const size_t hcol = c0 + w * 16 + g4 * 4;
    unsigned short* hout_base = hseq + (size_t)(b0 + row8) * 768 + hcol;
    const float* xp_base = xp + (size_t)(b0 + row8) * 1024 * 768 + hcol;
    const int soff = row8 * 1536 + (((int)hcol * 2) ^ (row8 << 4));
    const int rswz = row16 << 4;
    const bool owner = (row16 < 8);

    for (int t = 0; t < S_; ++t) {
      char* lb = (char*)((t & 1) ? hs1 : hs0);
      const float* xpp = xp_base + (size_t)t * 768;
      uint4 xv;
      // issue xp load (sc1, overlapped with the h-poll below)
      asm volatile("global_load_dwordx4 %0, %1, off sc1" : "=&v"(xv) : "v"(xpp));
      const unsigned short* hin = hseq + (size_t)t * (B_ * H_);
      if (t == 0) {
        uint4 cv0[2];
        int nj = (tid < 256) ? 2 : 1;
#pragma unroll
        for (int j = 0; j < 2; ++j) {
          if (j < nj) {
            int ch = (j == 0) ? tid : (512 + (tid & 255));
            int row = ch / 96;
            int col8 = ch - row * 96;
            asm volatile("global_load_dwordx4 %0, %1, off sc1"
                         : "=&v"(cv0[j])
                         : "v"(hin + (size_t)(b0 + row) * 768 + col8 * 8));
          }
        }
        asm volatile("s_waitcnt vmcnt(0)" ::: "memory");
        __builtin_amdgcn_sched_barrier(0);
#pragma unroll
        for (int j = 0; j < 2; ++j) {
          if (j < nj) {
            int ch = (j == 0) ? tid : (512 + (tid & 255));
            int row = ch / 96;
            int col8 = ch - row * 96;
            *(uint4*)(lb + row * 1536 + ((col8 * 16) ^ ((row & 7) << 4))) =
                cv0[j];
          }
        }
      } else {
        uint4 cv[2];
        unsigned done = 0;
        const unsigned full = (nch == 2) ? 3u : 1u;
        while (done != full) {
          if (!(done & 1))
            asm volatile("global_load_dwordx4 %0, %1, off sc1"
                         : "=&v"(cv[0]) : "v"(hin + gF[0]));
          if (nch == 2 && !(done & 2))
            asm volatile("global_load_dwordx4 %0, %1, off sc1"
                         : "=&v"(cv[1]) : "v"(hin + gF[1]));
          asm volatile("s_waitcnt vmcnt(0)" ::: "memory");
          __builtin_amdgcn_sched_barrier(0);
          if (!(done & 1) && (cv[0].x | cv[0].y) != 0 &&
              (cv[0].z | cv[0].w) != 0) {
            done |= 1;
            *(uint4*)(lb + lF[0]) = cv[0];
          }
          if (nch == 2 && !(done & 2) && (cv[1].x | cv[1].y) != 0 &&
              (cv[1].z | cv[1].w) != 0) {
            done |= 2;
            *(uint4*)(lb + lF[1]) = cv[1];
          }
        }
      }
      // verify xp chunk ready (sentinel: workers never store a zero float)
      while (true) {
        asm volatile("s_waitcnt vmcnt(0)" ::: "memory");
        __builtin_amdgcn_sched_barrier(0);
        if (__all(((xv.x | xv.y) != 0) && ((xv.z | xv.w) != 0))) break;
        asm volatile("global_load_dwordx4 %0, %1, off sc1"
                     : "=&v"(xv) : "v"(xpp));
      }
      float4 xpv = __builtin_bit_cast(float4, xv);
      __syncthreads();

      uint4 hb[24];
      const char* rb = lb + row8 * 1536;
#pragma unroll
      for (int kb = 0; kb < 24; ++kb)
        hb[kb] = *(const uint4*)(rb + ((kb * 64 + g4 * 16) ^ rswz));

      f32x4 acc0 = {xpv.x, xpv.y, xpv.z, xpv.w};
      f32x4 acc1 = {0.f, 0.f, 0.f, 0.f};
      f32x4 acc2 = {0.f, 0.f, 0.f, 0.f};
      f32x4 acc3 = {0.f, 0.f, 0.f, 0.f};
#pragma unroll
      for (int kb = 0; kb < 24; kb += 4) {
        acc0 = __builtin_amdgcn_mfma_f32_16x16x32_bf16(
            __builtin_bit_cast(s16x8, wfrag[kb]),
            __builtin_bit_cast(s16x8, hb[kb]), acc0, 0, 0, 0);
        acc1 = __builtin_amdgcn_mfma_f32_16x16x32_bf16(
            __builtin_bit_cast(s16x8, wfrag[kb + 1]),
            __builtin_bit_cast(s16x8, hb[kb + 1]), acc1, 0, 0, 0);
        acc2 = __builtin_amdgcn_mfma_f32_16x16x32_bf16(
            __builtin_bit_cast(s16x8, wfrag[kb + 2]),
            __builtin_bit_cast(s16x8, hb[kb + 2]), acc2, 0, 0, 0);
        acc3 = __builtin_amdgcn_mfma_f32_16x16x32_bf16(
            __builtin_bit_cast(s16x8, wfrag[kb + 3]),
            __builtin_bit_cast(s16x8, hb[kb + 3]), acc3, 0, 0, 0);
      }
      f32x4 g = (acc0 + acc1) + (acc2 + acc3);
      float t0 = fast_tanh(g[0]), t1 = fast_tanh(g[1]);
      float t2 = fast_tanh(g[2]), t3 = fast_tanh(g[3]);
      unsigned long long pk = (unsigned long long)f2b(t0)
          | ((unsigned long long)f2b(t1) << 16)
          | ((unsigned long long)f2b(t2) << 32)
          | ((unsigned long long)f2b(t3) << 48);
      if (pk == 0) pk = 1;

      if (owner)
        *(unsigned long long*)((char*)((t & 1) ? hs0 : hs1) + soff) = pk;

      unsigned long long po = __shfl(pk, l ^ 16);
      if (owner && (g4 & 1) == 0) {
        u32x4 st;
        st[0] = (unsigned)pk;
        st[1] = (unsigned)(pk >> 32);
        st[2] = (unsigned)po;
        st[3] = (unsigned)(po >> 32);
        asm volatile("global_store_dwordx4 %0, %1, off sc1" ::"v"(
                         hout_base + (size_t)(t + 1) * (B_ * H_)),
                     "v"(st)
                     : "memory");
      }
    }
  } else {
    // ---------------- workers: gemm0 (xp) + gemm1 (logits) ----------------
    unsigned short* As = (unsigned short*)smem;  // 128 x 64
    unsigned short* Bs = As + 128 * 64;          // 256 x 64
    const int wb = blockIdx.x - 48;
    const int wm = w >> 2, wn = w & 3;
    const int swz = (l & 7) << 3;

    for (int q = wb; q < NTILE; q += NWRK) {
      int slot = q / 192;
      int idx = q - slot * 192;
      int kind, band;  // kind 0 = gemm0 (xp), 1 = gemm1 (logits)
      if (slot < 2) {
        kind = 0; band = slot;
      } else if (slot < 14) {
        kind = (slot & 1) ? 0 : 1;
        band = (slot >> 1) + ((slot & 1) ? 1 : -1);
      } else {
        kind = 1; band = slot - 8;
      }
      int b = idx / 3;
      int ns = idx - b * 3;
      int s0 = band * 128;
      int r0 = b * 1024 + s0;
      int n0 = ns * 256;

      if (kind == 1) wait_rows(hseq, s0 + 128, b);

      const unsigned short* Bw = (kind == 0) ? wih : wfc;
      f32x4 acc[4][4] = {};
      for (int k0 = 0; k0 < 768; k0 += 64) {
        if (tid < 256) {  // A-stage: 128 rows
          int srow = tid >> 1;
          int shalf = (tid & 1) * 32;
          int swrow = (srow & 7) << 3;
          if (kind == 0) {  // x fp32 -> bf16
            const float* Af = x + (size_t)(r0 + srow) * 768 + k0 + shalf;
#pragma unroll
            for (int jj = 0; jj < 4; ++jj) {
              float4 v0 = *(const float4*)(Af + jj * 8);
              float4 v1 = *(const float4*)(Af + jj * 8 + 4);
              uint4 p;
              p.x = f2b(v0.x) | ((unsigned)f2b(v0.y) << 16);
              p.y = f2b(v0.z) | ((unsigned)f2b(v0.w) << 16);
              p.z = f2b(v1.x) | ((unsigned)f2b(v1.y) << 16);
              p.w = f2b(v1.z) | ((unsigned)f2b(v1.w) << 16);
              int c = (shalf + jj * 8) ^ swrow;
              *(uint4*)(As + srow * 64 + c) = p;
            }
          } else {  // hseq bf16, row-gathered, sc1
            int ar = r0 + srow;
            const unsigned short* Ab =
                hseq + ((size_t)((ar & 1023) + 1) * 64 + (ar >> 10)) * 768 +
                k0 + shalf;
            uint4 pa[4];
#pragma unroll
            for (int jj = 0; jj < 4; ++jj)
              asm volatile("global_load_dwordx4 %0, %1, off sc1"
                           : "=&v"(pa[jj]) : "v"(Ab + jj * 8));
            asm volatile("s_waitcnt vmcnt(0)" ::: "memory");
            __builtin_amdgcn_sched_barrier(0);
#pragma unroll
            for (int jj = 0; jj < 4; ++jj) {
              int c = (shalf + jj * 8) ^ swrow;
              *(uint4*)(As + srow * 64 + c) = pa[jj];
            }
          }
        } else {  // B-stage: 256 rows, 1 thread/row
          int u = tid & 255;
          const unsigned short* Bb = Bw + (size_t)(n0 + u) * 768 + k0;
          int swrow = (u & 7) << 3;
#pragma unroll
          for (int hh = 0; hh < 2; ++hh) {
            int shalf = hh * 32;
#pragma unroll
            for (int jj = 0; jj < 4; ++jj) {
              uint4 p = *(const uint4*)(Bb + shalf + jj * 8);
              int c = (shalf + jj * 8) ^ swrow;
              *(uint4*)(Bs + u * 64 + c) = p;
            }
          }
        }
        __syncthreads();
#pragma unroll
        for (int kb = 0; kb < 2; ++kb) {
          int ccol = (kb * 32 + g4 * 8) ^ swz;
          s16x8 af[4], bfr[4];
#pragma unroll
          for (int mi = 0; mi < 4; ++mi)
            af[mi] = __builtin_bit_cast(
                s16x8,
                *(const uint4*)(As + (wm * 64 + mi * 16 + row16) * 64 + ccol));
#pragma unroll
          for (int ni = 0; ni < 4; ++ni)
            bfr[ni] = __builtin_bit_cast(
                s16x8,
                *(const uint4*)(Bs + (wn * 64 + ni * 16 + row16) * 64 + ccol));
#pragma unroll
          for (int mi = 0; mi < 4; ++mi)
#pragma unroll
            for (int ni = 0; ni < 4; ++ni)
              acc[mi][ni] = __builtin_amdgcn_mfma_f32_16x16x32_bf16(
                  af[mi], bfr[ni], acc[mi][ni], 0, 0, 0);
        }
        __syncthreads();
      }
      if (kind == 0) {  // xp epilogue: sc1 + never-zero sentinel
#pragma unroll
        for (int ni = 0; ni < 4; ++ni) {
          int col = n0 + wn * 64 + ni * 16 + row16;
          float bv = b_ih[col] + b_hh[col];
#pragma unroll
          for (int mi = 0; mi < 4; ++mi) {
            int rbase = r0 + wm * 64 + mi * 16 + g4 * 4;
#pragma unroll
            for (int i = 0; i < 4; ++i) {
              float v = acc[mi][ni][i] + bv;
              unsigned uu = __builtin_bit_cast(unsigned, v);
              uu |= (unsigned)(uu == 0);
              asm volatile("global_store_dword %0, %1, off sc1" ::"v"(
                               xp + (size_t)(rbase + i) * 768 + col),
                           "v"(uu)
                           : "memory");
            }
          }
        }
      } else {  // logits epilogue: plain stores
#pragma unroll
        for (int ni = 0; ni < 4; ++ni) {
          int col = n0 + wn * 64 + ni * 16 + row16;
          float bv = b_fc[col];
#pragma unroll
          for (int mi = 0; mi < 4; ++mi) {
            int rbase = r0 + wm * 64 + mi * 16 + g4 * 4;
#pragma unroll
            for (int i = 0; i < 4; ++i)
              out[(size_t)(rbase + i) * 768 + col] = acc[mi][ni][i] + bv;
          }
        }
      }
    }
    // tail fold (worker 0): final hidden bf16 -> f32 after h[1024] complete
    if (wb == 0) {
      for (int g = 0; g < GB; ++g) wait_rows(hseq, 1024, g * 8);
      const unsigned short* hfin = hseq + (size_t)S_ * B_ * H_;
      for (int i = tid; i < (B_ * H_) / 8; i += 512) {
        uint4 v = *(const uint4*)(hfin + i * 8);
        float4 o0, o1;
        o0.x = b2f((unsigned short)(v.x & 0xFFFF));
        o0.y = b2f((unsigned short)(v.x >> 16));
        o0.z = b2f((unsigned short)(v.y & 0xFFFF));
        o0.w = b2f((unsigned short)(v.y >> 16));
        o1.x = b2f((unsigned short)(v.z & 0xFFFF));
        o1.y = b2f((unsigned short)(v.z >> 16));
        o1.z = b2f((unsigned short)(v.w & 0xFFFF));
        o1.w = b2f((unsigned short)(v.w >> 16));
        *(float4*)(hfin_out + i * 8) = o0;
        *(float4*)(hfin_out + i * 8 + 4) = o1;
      }
    }
  }
}

extern "C" void kernel_launch(void* const* d_in, const int* in_sizes, int n_in,
                              void* d_out, int out_size, void* d_ws,
                              size_t ws_size, hipStream_t stream) {
  const float* hidden = (const float*)d_in[0];
  const float* x = (const float*)d_in[1];
  const float* W_ih = (const float*)d_in[2];
  const float* W_hh = (const float*)d_in[3];
  const float* b_ih = (const float*)d_in[4];
  const float* b_hh = (const float*)d_in[5];
  const float* W_fc = (const float*)d_in[6];
  const float* b_fc = (const float*)d_in[7];
  float* out = (float*)d_out;
  float* xp = out;  // xp aliases the logits region; data-as-flag => zeroed
                    // each launch; logits overwrite band-by-band after the
                    // scan has consumed those xp rows (gated via h)

  char* ws = (char*)d_ws;
  unsigned short* hseq = (unsigned short*)ws;  // [(S+1)][B][H] bf16
  size_t hseq_elems = (size_t)(S_ + 1) * B_ * H_;
  unsigned short* wih_b = hseq + hseq_elems;
  unsigned short* wfc_b = wih_b + 768 * 768;

  // zero h[1..S] and the xp region: both are data-as-flag surfaces and the
  // harness does not re-poison buffers between replays
  (void)hipMemsetAsync(hseq + (size_t)B_ * H_, 0, (size_t)S_ * B_ * H_ * 2,
                       stream);
  (void)hipMemsetAsync(xp, 0, (size_t)B_ * S_ * H_ * 4, stream);
  prep_kernel<<<1200, 256, 0, stream>>>(W_ih, W_fc, hidden, wih_b, wfc_b,
                                        hseq);
  fused_kernel<<<256, 512, 0, stream>>>(W_hh, x, wih_b, xp, hseq, wfc_b, b_ih,
                                        b_hh, b_fc, out,
                                        out + (size_t)65536 * 768);
}